// Round 9
// baseline (2831.418 us; speedup 1.0000x reference)
//
#include <hip/hip_runtime.h>

#define NN1 60000
#define EE1 600000
#define NN2 20000
#define EE2 150000
#define AA  60000

__device__ __forceinline__ float sigf(float x){ return 1.f/(1.f+expf(-x)); }
// wave-uniform broadcast of lane sl's value. sl may be a RUNTIME uniform
// (v_readlane_b32 takes an SGPR lane index), so loops need not unroll.
__device__ __forceinline__ float rlane(float v, int sl){
  return __int_as_float(__builtin_amdgcn_readlane(__float_as_int(v), sl));
}
// Broadcast 4 channels of float4 V held by lane SL, then FMA into named scalars.
// ALL state is named scalars -> guaranteed VGPRs (rounds 1/3: arrays spill).
#define RL4V(V, SL) hx = rlane(V.x, SL); hy = rlane(V.y, SL); hz = rlane(V.z, SL); hw = rlane(V.w, SL);
#define RL4(SL) RL4V(ld, SL)
#define FMA4(A, W) A = fmaf(hx, W.x, A); A = fmaf(hy, W.y, A); A = fmaf(hz, W.z, A); A = fmaf(hw, W.w, A);

// ---------- elementwise ----------
__global__ void k_relu(float* a, int n){
  int i = blockIdx.x*blockDim.x + threadIdx.x;
  if (i < n) a[i] = fmaxf(a[i], 0.f);
}
__global__ void k_copy(const float* __restrict__ a, float* __restrict__ o, int n){
  int i = blockIdx.x*blockDim.x + threadIdx.x;
  if (i < n) o[i] = a[i];
}

// ---------- edge type ----------
__global__ void k_etype(const float* __restrict__ ea, int* __restrict__ etype, int E){
  int e = blockIdx.x*blockDim.x + threadIdx.x;
  if (e >= E) return;
  const float* p = ea + (size_t)e*10;
  float best = p[0]; int bi = 0;
  #pragma unroll
  for (int k = 1; k < 4; ++k){ float v = p[k]; if (v > best){ best = v; bi = k; } }
  etype[e] = bi;
}

__global__ void k_coeff(const float* __restrict__ nt, const int* __restrict__ node_type,
                        float* __restrict__ coeff, int N){
  int n = blockIdx.x*blockDim.x + threadIdx.x;
  if (n < N) coeff[n] = nt[node_type[n]];
}

// ---------- batch row pointers (batch sorted ascending) ----------
__global__ void k_batchptr(const int* __restrict__ batch, int* __restrict__ rb, int N, int B){
  int n = blockIdx.x*blockDim.x + threadIdx.x;
  if (n >= N) return;
  int b = batch[n];
  if (n == 0){ for (int g = 0; g <= b; ++g) rb[g] = 0; }
  else {
    int pb = batch[n-1];
    for (int g = pb+1; g <= b; ++g) rb[g] = n;
  }
  if (n == N-1){ for (int g = b+1; g <= B; ++g) rb[g] = N; }
}

// ---------- weight prep ----------
// msg weights: conv_w[m][c][d] (m = (li*3+l)*4+t) -> w4[m][c4][d][q],
// float4 element (c4,d) = { W[4c4+0][d], W[4c4+1][d], W[4c4+2][d], W[4c4+3][d] }.
// In-kernel lane d reads float4 index c4*64+d: contiguous -> conflict-free b128.
__global__ void k_prep_msgw(const float* __restrict__ w, float* __restrict__ w4){
  int idx = blockIdx.x*256 + threadIdx.x;   // 60*4096 = 245760
  if (idx >= 245760) return;
  int m = idx >> 12, r = idx & 4095;
  int c4 = r >> 8, d = (r >> 2) & 63, q = r & 3;
  w4[idx] = w[m*4096 + (4*c4+q)*64 + d];
}
// GRU weights, three layouts:
//  wihT[l][t][c4][d][q] = wih[l][(64t+d)][4c4+q]  (tr3 fallback: lane d owns row 64t+d)
//  wihW[l][c4][j][q]    = wih[l][j][4c4+q]        (fused: lane l owns rows {l,64+l,128+l})
//  whh4[l][c4][j][q]    = whh[l][j][4c4+q]
__global__ void k_prep_gruw(const float* __restrict__ wih, const float* __restrict__ whh,
                            float* __restrict__ wihT, float* __restrict__ wihW,
                            float* __restrict__ whh4){
  int idx = blockIdx.x*256 + threadIdx.x;   // 5*12288 = 61440 each
  if (idx >= 61440) return;
  {
    int l = idx / 12288, r = idx % 12288;
    int t = r >> 12, rr = r & 4095;
    int c4 = rr >> 8, d = (rr >> 2) & 63, q = rr & 3;
    wihT[idx] = wih[l*12288 + (64*t + d)*64 + 4*c4 + q];
  }
  {
    int l = idx / 12288, rr = idx % 12288;
    int e = rr >> 2, q = rr & 3;
    int c4 = e / 192, j = e - c4*192;
    wihW[idx] = wih[l*12288 + j*64 + 4*c4 + q];
    whh4[idx] = whh[l*12288 + j*64 + 4*c4 + q];
  }
}

// ---------- set2set LSTM weight transpose to [k][j] (coalesced over gate row j) ----------
__global__ void k_s2strans(const float* __restrict__ wih0, const float* __restrict__ whh0,
                           const float* __restrict__ wih1, const float* __restrict__ whh1,
                           float* __restrict__ T){
  int idx = blockIdx.x*256 + threadIdx.x;
  if (idx < 32768){ int k = idx >> 8, j = idx & 255; T[idx] = wih0[j*128 + k]; }
  else if (idx < 49152){ int r = idx - 32768; int k = r >> 8, j = r & 255; T[idx] = whh0[j*64 + k]; }
  else if (idx < 65536){ int r = idx - 49152; int k = r >> 8, j = r & 255; T[idx] = wih1[j*64 + k]; }
  else if (idx < 81920){ int r = idx - 65536; int k = r >> 8, j = r & 255; T[idx] = whh1[j*64 + k]; }
}

// ---------- CSR build ----------
__global__ void k_hist(const int* __restrict__ dst, int* __restrict__ cnt, int E){
  int e = blockIdx.x*blockDim.x + threadIdx.x;
  if (e >= E) return;
  atomicAdd(&cnt[dst[e]], 1);
}
__global__ void k_chunksum(const int* __restrict__ cnt, int* __restrict__ csum, int M){
  __shared__ int sh[256];
  int base = blockIdx.x*1024;
  int s = 0;
  for (int i = threadIdx.x; i < 1024; i += 256){
    int idx = base + i;
    if (idx < M) s += cnt[idx];
  }
  sh[threadIdx.x] = s;
  __syncthreads();
  for (int o = 128; o; o >>= 1){
    if (threadIdx.x < o) sh[threadIdx.x] += sh[threadIdx.x + o];
    __syncthreads();
  }
  if (threadIdx.x == 0) csum[blockIdx.x] = sh[0];
}
__global__ void k_chunkscan(int* __restrict__ csum, int nchunk){
  __shared__ int sh[256];
  int i = threadIdx.x;
  int v = (i < nchunk) ? csum[i] : 0;
  sh[i] = v; __syncthreads();
  for (int o = 1; o < 256; o <<= 1){
    int y = (i >= o) ? sh[i-o] : 0;
    __syncthreads();
    sh[i] += y;
    __syncthreads();
  }
  if (i < nchunk) csum[i] = sh[i] - v;
  if (i == 255) csum[nchunk] = sh[255];
}
__global__ void k_chunkapply(const int* __restrict__ cnt, const int* __restrict__ csum,
                             int* __restrict__ R, int* __restrict__ cur, int M){
  __shared__ int sh[256];
  int base = blockIdx.x*1024;
  int i0 = base + threadIdx.x*4;
  int v[4]; int s = 0;
  #pragma unroll
  for (int k = 0; k < 4; ++k){ int idx = i0 + k; v[k] = (idx < M) ? cnt[idx] : 0; s += v[k]; }
  sh[threadIdx.x] = s; __syncthreads();
  for (int o = 1; o < 256; o <<= 1){
    int y = (threadIdx.x >= o) ? sh[threadIdx.x-o] : 0;
    __syncthreads();
    sh[threadIdx.x] += y;
    __syncthreads();
  }
  int run = csum[blockIdx.x] + sh[threadIdx.x] - s;
  #pragma unroll
  for (int k = 0; k < 4; ++k){
    int idx = i0 + k;
    if (idx < M){ R[idx] = run; cur[idx] = run; run += v[k]; }
  }
  if (threadIdx.x == 255 && base + 1024 >= M) R[M] = csum[blockIdx.x] + sh[255];
}
__global__ void k_scatter(const int* __restrict__ src, const int* __restrict__ dst,
                          const int* __restrict__ etype, int* __restrict__ cur,
                          int* __restrict__ ep, int E){
  int e = blockIdx.x*blockDim.x + threadIdx.x;
  if (e >= E) return;
  int t = etype ? etype[e] : 0;
  int pos = atomicAdd(&cur[dst[e]], 1);
  ep[pos] = (t << 20) | src[e];
}

// ---------- sweep-first message pass (round 9) ----------
// Algebra: aggr = sum_t W_t s_t with s_t[d] = sum_{e of type t -> d} coeff*h[src].
// Round-7 lesson: fusing gather+transform kills occupancy (64KB LDS on the
// latency-bound gather). Round-8 residual: sweep_p gathers 153MB logical from
// the 61MB tr footprint in L3 (~2TB/s, latency-bound). Split the OTHER way:
// (1) k_sweep4s gathers h DIRECTLY (15MB hot footprint) -> s[d][t][64];
//     sweep_p structure (1 dst/wave, no LDS, tiny VGPR = high occupancy).
// (2) k_tr4s transforms s -> aggr densely (contiguous 4KB/group reads).

__global__ void k_sweep4s(const float* __restrict__ h, const int* __restrict__ R,
                          const int* __restrict__ ep, const float* __restrict__ coeff,
                          float* __restrict__ s4, int N){
  int w = threadIdx.x >> 6, lane = threadIdx.x & 63;
  int d = blockIdx.x*4 + w;
  if (d >= N) return;
  int p = R[d], pend = R[d+1];
  float a0=0.f, a1=0.f, a2=0.f, a3=0.f;
  while (p < pend){
    int m = pend - p; if (m > 64) m = 64;
    int ev = (lane < m) ? ep[p + lane] : 0;
    for (int j = 0; j < m; ++j){
      int pk = __builtin_amdgcn_readfirstlane(__shfl(ev, j));
      int sI = pk & 0xFFFFF, t = pk >> 20;
      float v = h[((size_t)sI << 6) + lane] * coeff[sI];
      if (t == 0) a0 += v;
      else if (t == 1) a1 += v;
      else if (t == 2) a2 += v;
      else a3 += v;
    }
    p += m;
  }
  float* o = s4 + ((size_t)d << 8) + lane;   // s[d][t][64], 1KB/dst contiguous
  o[0] = a0; o[64] = a1; o[128] = a2; o[192] = a3;
}

// dense transform of s -> aggr: aggr[n][lane] = sum_t sum_c W_t[c][lane] s[n][t][c].
// Per 4-node group: 4 coalesced dwordx4 loads (4KB contiguous), 64 LDS weight
// reads, 1024 rl + 1024 fma, named scalars. 64KB LDS, 1024 thr (tr4d-proven
// config: 1 block/CU, 4 waves/SIMD — fine for a dense streamed kernel).
__global__ __launch_bounds__(1024, 4) void k_tr4s(
    const float* __restrict__ s4, const float* __restrict__ W4,
    float* __restrict__ aggr, int N){
  extern __shared__ float4 wl[];           // [4][1024] = 64 KB
  for (int i = threadIdx.x; i < 4096; i += 1024) wl[i] = ((const float4*)W4)[i];
  __syncthreads();
  int lane = threadIdx.x & 63, wv = threadIdx.x >> 6;   // 16 waves
  int ng = N >> 2, stride = gridDim.x*16;
  const float4* sf4 = (const float4*)s4;
  for (int g = blockIdx.x*16 + wv; g < ng; g += stride){
    // ld_k covers node (4g+k): lane sl=(t<<4)|c4 holds s[4g+k][t][4c4..4c4+3]
    float4 ld0 = sf4[(size_t)g*256 + lane];
    float4 ld1 = sf4[(size_t)g*256 + 64 + lane];
    float4 ld2 = sf4[(size_t)g*256 + 128 + lane];
    float4 ld3 = sf4[(size_t)g*256 + 192 + lane];
    float a0=0.f, a1=0.f, a2=0.f, a3=0.f;
    for (int c4 = 0; c4 < 16; ++c4){
      int wb = (c4 << 6) + lane;
      float4 w0 = wl[wb], w1 = wl[1024+wb], w2 = wl[2048+wb], w3 = wl[3072+wb];
      float hx, hy, hz, hw;
      RL4V(ld0, c4)     FMA4(a0, w0)
      RL4V(ld0, 16|c4)  FMA4(a0, w1)
      RL4V(ld0, 32|c4)  FMA4(a0, w2)
      RL4V(ld0, 48|c4)  FMA4(a0, w3)
      RL4V(ld1, c4)     FMA4(a1, w0)
      RL4V(ld1, 16|c4)  FMA4(a1, w1)
      RL4V(ld1, 32|c4)  FMA4(a1, w2)
      RL4V(ld1, 48|c4)  FMA4(a1, w3)
      RL4V(ld2, c4)     FMA4(a2, w0)
      RL4V(ld2, 16|c4)  FMA4(a2, w1)
      RL4V(ld2, 32|c4)  FMA4(a2, w2)
      RL4V(ld2, 48|c4)  FMA4(a2, w3)
      RL4V(ld3, c4)     FMA4(a3, w0)
      RL4V(ld3, 16|c4)  FMA4(a3, w1)
      RL4V(ld3, 32|c4)  FMA4(a3, w2)
      RL4V(ld3, 48|c4)  FMA4(a3, w3)
    }
    float* o = aggr + (((size_t)g) << 8) + lane;
    o[0] = a0; o[64] = a1; o[128] = a2; o[192] = a3;
  }
}

// fallback if 64KB dynamic LDS refused: one matrix per pass, 16KB static.
__global__ __launch_bounds__(256) void k_tr1s(
    const float* __restrict__ s4, const float* __restrict__ W4,
    float* __restrict__ aggr, int N, int t, int first){
  __shared__ float4 wl[1024];
  for (int i = threadIdx.x; i < 1024; i += 256) wl[i] = ((const float4*)W4)[i];
  __syncthreads();
  int lane = threadIdx.x & 63, w = threadIdx.x >> 6;
  int ng = N >> 2, stride = gridDim.x*4;
  const float4* sf4 = (const float4*)s4;
  for (int g = blockIdx.x*4 + w; g < ng; g += stride){
    // lane l holds s[4g+(l>>4)][t][4(l&15)..+3]
    float4 ld = sf4[((size_t)(16*g + 4*(lane>>4) + t) << 4) + (lane & 15)];
    float* o = aggr + (((size_t)g) << 8) + lane;
    float a0 = first ? 0.f : o[0];
    float a1 = first ? 0.f : o[64];
    float a2 = first ? 0.f : o[128];
    float a3 = first ? 0.f : o[192];
    for (int c4 = 0; c4 < 16; ++c4){
      float4 w0 = wl[(c4 << 6) + lane];
      float hx, hy, hz, hw;
      RL4(c4)       FMA4(a0, w0)
      RL4(16|c4)    FMA4(a1, w0)
      RL4(32|c4)    FMA4(a2, w0)
      RL4(48|c4)    FMA4(a3, w0)
    }
    o[0] = a0; o[64] = a1; o[128] = a2; o[192] = a3;
  }
}

// ---------- level-2 path (single type): transform then gather (unchanged r6) ----------
__global__ __launch_bounds__(256) void k_tr1(
    const float* __restrict__ h, const float* __restrict__ W4,
    const float* __restrict__ coeff, float* __restrict__ tr, int N){
  __shared__ float4 wl[1024];                 // 16 KB
  for (int i = threadIdx.x; i < 1024; i += 256) wl[i] = ((const float4*)W4)[i];
  __syncthreads();
  int lane = threadIdx.x & 63, w = threadIdx.x >> 6;
  int ng = N >> 2, stride = gridDim.x*4;
  for (int g = blockIdx.x*4 + w; g < ng; g += stride){
    int n0 = g << 2;
    float4 ld = ((const float4*)(h + ((size_t)n0 << 6)))[lane];
    float a0=0.f, a1=0.f, a2=0.f, a3=0.f;
    for (int c4 = 0; c4 < 16; ++c4){
      float4 w0 = wl[(c4 << 6) + lane];
      float hx, hy, hz, hw;
      RL4(c4)       FMA4(a0, w0)
      RL4(16|c4)    FMA4(a1, w0)
      RL4(32|c4)    FMA4(a2, w0)
      RL4(48|c4)    FMA4(a3, w0)
    }
    if (coeff){
      float4 cv = ((const float4*)coeff)[g];
      a0 *= cv.x; a1 *= cv.y; a2 *= cv.z; a3 *= cv.w;
    }
    float* o0 = tr + ((size_t)n0 << 6) + lane;
    o0[0] = a0; o0[64] = a1; o0[128] = a2; o0[192] = a3;
  }
}

__global__ void k_sweep_p(const float* __restrict__ tr, const int* __restrict__ R,
                          const int* __restrict__ ep, float* __restrict__ aggr, int N){
  int w = threadIdx.x >> 6, lane = threadIdx.x & 63;
  int d = blockIdx.x*4 + w;
  if (d >= N) return;
  int p = R[d], pend = R[d+1];
  float acc = 0.f;
  while (p < pend){
    int m = pend - p; if (m > 64) m = 64;
    int ev = (lane < m) ? ep[p + lane] : 0;
    for (int j = 0; j < m; ++j){
      int pk = __shfl(ev, j);
      int s = pk & 0xFFFFF, t = pk >> 20;
      acc += tr[((size_t)t*N + s)*64 + lane];
    }
    p += m;
  }
  aggr[(size_t)d*64 + lane] = acc;
}

// ---------- tr3: GRU-fallback gi transform (LDS weights + readlane) ----------
__global__ __launch_bounds__(256) void k_tr3(
    const float* __restrict__ h, const float* __restrict__ W4,
    float* __restrict__ tr, int N){
  __shared__ float4 wl[3072];                 // 48 KB (3 matrices)
  for (int i = threadIdx.x; i < 3072; i += 256) wl[i] = ((const float4*)W4)[i];
  __syncthreads();
  int lane = threadIdx.x & 63, w = threadIdx.x >> 6;
  int ng = N >> 2, stride = gridDim.x*4;
  for (int g = blockIdx.x*4 + w; g < ng; g += stride){
    int n0 = g << 2;
    float4 ld = ((const float4*)(h + ((size_t)n0 << 6)))[lane];
    float a00=0.f,a01=0.f,a02=0.f,a03=0.f;
    float a10=0.f,a11=0.f,a12=0.f,a13=0.f;
    float a20=0.f,a21=0.f,a22=0.f,a23=0.f;
    for (int c4 = 0; c4 < 16; ++c4){
      float4 w0 = wl[(c4 << 6) + lane];
      float4 w1 = wl[1024 + (c4 << 6) + lane];
      float4 w2 = wl[2048 + (c4 << 6) + lane];
      float hx, hy, hz, hw;
      RL4(c4)       FMA4(a00, w0) FMA4(a10, w1) FMA4(a20, w2)
      RL4(16|c4)    FMA4(a01, w0) FMA4(a11, w1) FMA4(a21, w2)
      RL4(32|c4)    FMA4(a02, w0) FMA4(a12, w1) FMA4(a22, w2)
      RL4(48|c4)    FMA4(a03, w0) FMA4(a13, w1) FMA4(a23, w2)
    }
    float* o0 = tr + ((size_t)n0 << 6) + lane;
    o0[0] = a00; o0[64] = a01; o0[128] = a02; o0[192] = a03;
    float* o1 = tr + (((size_t)N + n0) << 6) + lane;
    o1[0] = a10; o1[64] = a11; o1[128] = a12; o1[192] = a13;
    float* o2 = tr + (((size_t)2*N + n0) << 6) + lane;
    o2[0] = a20; o2[64] = a21; o2[128] = a22; o2[192] = a23;
  }
}

// ---------- fully fused GRU: both GEMVs + pointwise in ONE kernel ----------
// wih AND whh in LDS (96KB, 1 block/CU, 16 waves = 4/SIMD). GRU algebra folds
// gi_r+gh_r and gi_z+gh_z into single accumulators. Per 4-node group: 2
// coalesced dwordx4 loads, 96 conflict-free ds_read_b128, 512 rl + 1536 fma,
// in-lane pointwise, ZERO barriers in the loop.  [round 6: -950us]
#define RLAH(SL) \
  ax = rlane(la.x, SL); ay = rlane(la.y, SL); az2 = rlane(la.z, SL); aw = rlane(la.w, SL); \
  hx = rlane(ld.x, SL); hy = rlane(ld.y, SL); hz  = rlane(ld.z, SL); hw = rlane(ld.w, SL);
#define GACC(SL, R, Z, P, Q) RLAH(SL) \
  R = fmaf(ax,iwr.x,R); R = fmaf(ay,iwr.y,R); R = fmaf(az2,iwr.z,R); R = fmaf(aw,iwr.w,R); \
  R = fmaf(hx,hwr.x,R); R = fmaf(hy,hwr.y,R); R = fmaf(hz,hwr.z,R);  R = fmaf(hw,hwr.w,R); \
  Z = fmaf(ax,iwz.x,Z); Z = fmaf(ay,iwz.y,Z); Z = fmaf(az2,iwz.z,Z); Z = fmaf(aw,iwz.w,Z); \
  Z = fmaf(hx,hwz.x,Z); Z = fmaf(hy,hwz.y,Z); Z = fmaf(hz,hwz.z,Z);  Z = fmaf(hw,hwz.w,Z); \
  P = fmaf(ax,iwn.x,P); P = fmaf(ay,iwn.y,P); P = fmaf(az2,iwn.z,P); P = fmaf(aw,iwn.w,P); \
  Q = fmaf(hx,hwn.x,Q); Q = fmaf(hy,hwn.y,Q); Q = fmaf(hz,hwn.z,Q);  Q = fmaf(hw,hwn.w,Q);
#define GFIN(K, R, Z, P, Q) { \
    size_t off = base + ((size_t)(K) << 6) + lane; \
    float hv = h[off]; \
    float r = sigf(R), z = sigf(Z); \
    float nn = tanhf(P + r*Q); \
    h[off] = (1.f - z)*nn + z*hv; }
__global__ __launch_bounds__(1024, 4) void k_gru_fused(
    const float* __restrict__ aggr, float* __restrict__ h,
    const float* __restrict__ wihW, const float* __restrict__ whhW,
    const float* __restrict__ bih, const float* __restrict__ bhh, int N){
  extern __shared__ float4 wl[];           // [6144]: wih | whh, 96 KB
  for (int i = threadIdx.x; i < 6144; i += 1024)
    wl[i] = (i < 3072) ? ((const float4*)wihW)[i] : ((const float4*)whhW)[i - 3072];
  __syncthreads();
  const float4* wi = wl;
  const float4* wh = wl + 3072;
  int lane = threadIdx.x & 63, wv = threadIdx.x >> 6;
  float br  = bih[lane]     + bhh[lane];
  float bz  = bih[64+lane]  + bhh[64+lane];
  float bp  = bih[128+lane];                // gi_n bias
  float bq  = bhh[128+lane];                // gh_n bias
  int ng = N >> 2, stride = gridDim.x*16;
  for (int g = blockIdx.x*16 + wv; g < ng; g += stride){
    int n0 = g << 2;
    size_t base = (size_t)n0 << 6;
    float4 la = ((const float4*)(aggr + base))[lane];
    float4 ld = ((const float4*)(h + base))[lane];
    float r0=br, r1=br, r2=br, r3=br;
    float z0=bz, z1=bz, z2=bz, z3=bz;
    float p0=bp, p1=bp, p2=bp, p3=bp;
    float q0=bq, q1=bq, q2=bq, q3=bq;
    for (int c4 = 0; c4 < 16; ++c4){
      int wb = c4*192 + lane;
      float4 iwr = wi[wb], iwz = wi[wb+64], iwn = wi[wb+128];
      float4 hwr = wh[wb], hwz = wh[wb+64], hwn = wh[wb+128];
      float ax, ay, az2, aw, hx, hy, hz, hw;
      GACC(c4,    r0, z0, p0, q0)
      GACC(16|c4, r1, z1, p1, q1)
      GACC(32|c4, r2, z2, p2, q2)
      GACC(48|c4, r3, z3, p3, q3)
    }
    GFIN(0, r0, z0, p0, q0)
    GFIN(1, r1, z1, p1, q1)
    GFIN(2, r2, z2, p2, q2)
    GFIN(3, r3, z3, p3, q3)
  }
}

// ---------- GRU finalize fallback (used only if 96KB dynamic LDS refused) ----------
#define GRUACC(SL, RK, ZK, NK) RL4(SL) FMA4(RK, wr) FMA4(ZK, wz) FMA4(NK, wn)
#define GRUFIN(K, RK, ZK, NK) { \
    size_t off = base + (K << 6) + lane; \
    float gir = gi[off], giz = gi[S + off], gin = gi[2*S + off]; \
    float hv = h[off]; \
    float r = sigf(gir + bir + RK); \
    float z = sigf(giz + biz + ZK); \
    float nv = tanhf(gin + bin_ + r*NK); \
    h[off] = (1.f - z)*nv + z*hv; }
__global__ __launch_bounds__(256, 3) void k_gru_finW(
    const float* __restrict__ gi, float* __restrict__ h,
    const float* __restrict__ whh4,
    const float* __restrict__ bih, const float* __restrict__ bhh, int N){
  __shared__ float4 wh[3072];              // [c4][192] = whh[j][4c4+q], 48KB
  for (int i = threadIdx.x; i < 3072; i += 256) wh[i] = ((const float4*)whh4)[i];
  __syncthreads();
  int lane = threadIdx.x & 63, w = threadIdx.x >> 6;
  float bir = bih[lane], biz = bih[64+lane], bin_ = bih[128+lane];
  float bhr = bhh[lane], bhz = bhh[64+lane], bhn = bhh[128+lane];
  size_t S = (size_t)N << 6;
  int ng = N >> 2, stride = gridDim.x*4;
  for (int g = blockIdx.x*4 + w; g < ng; g += stride){
    int n0 = g << 2;
    size_t base = (size_t)n0 << 6;
    float4 ld = ((const float4*)(h + base))[lane];
    float ar0=bhr, ar1=bhr, ar2=bhr, ar3=bhr;
    float az0=bhz, az1=bhz, az2=bhz, az3=bhz;
    float an0=bhn, an1=bhn, an2=bhn, an3=bhn;
    for (int c4 = 0; c4 < 16; ++c4){
      int wb = c4*192 + lane;
      float4 wr = wh[wb];
      float4 wz = wh[wb + 64];
      float4 wn = wh[wb + 128];
      float hx, hy, hz, hw;
      GRUACC(c4,    ar0, az0, an0)
      GRUACC(16|c4, ar1, az1, an1)
      GRUACC(32|c4, ar2, az2, an2)
      GRUACC(48|c4, ar3, az3, an3)
    }
    GRUFIN(0, ar0, az0, an0)
    GRUFIN(1, ar1, az1, an1)
    GRUFIN(2, ar2, az2, an2)
    GRUFIN(3, ar3, az3, an3)
  }
}

// ---------- batch norm over nodes ----------
__global__ void k_bnstats(const float* __restrict__ h, float* __restrict__ stats, int N){
  int c = threadIdx.x & 63;
  int g = threadIdx.x >> 6;
  float s = 0.f, s2 = 0.f;
  for (int n = blockIdx.x*4 + g; n < N; n += gridDim.x*4){
    float v = h[(size_t)n*64 + c]; s += v; s2 += v*v;
  }
  __shared__ float sh[4][64], sh2[4][64];
  sh[g][c] = s; sh2[g][c] = s2;
  __syncthreads();
  if (g == 0){
    float ts = sh[0][c]+sh[1][c]+sh[2][c]+sh[3][c];
    float t2 = sh2[0][c]+sh2[1][c]+sh2[2][c]+sh2[3][c];
    atomicAdd(&stats[c], ts); atomicAdd(&stats[64+c], t2);
  }
}
__global__ void k_bnapply(float* __restrict__ h, const float* __restrict__ stats,
                          const float* __restrict__ g, const float* __restrict__ b,
                          int N, int relu){
  int i = blockIdx.x*blockDim.x + threadIdx.x;
  if (i >= N*64) return;
  int c = i & 63;
  float inv = 1.f/(float)N;
  float mean = stats[c]*inv;
  float var  = stats[64+c]*inv - mean*mean;
  float y = (h[i]-mean)*rsqrtf(var + 1e-5f)*g[c] + b[c];
  if (relu) y = fmaxf(y, 0.f);
  h[i] = y;
}

// ---------- avg_pool ----------
__global__ void k_pool_acc(const float* __restrict__ h, const int* __restrict__ asrc,
                           const int* __restrict__ adst, float* __restrict__ h2,
                           float* __restrict__ cnt, int A){
  int i = blockIdx.x*blockDim.x + threadIdx.x;
  if (i >= A*64) return;
  int a = i >> 6, c = i & 63;
  int s = asrc[a], d = adst[a];
  atomicAdd(&h2[(size_t)d*64 + c], h[(size_t)s*64 + c]);
  if (c == 0) atomicAdd(&cnt[d], 1.f);
}
__global__ void k_pool_div(float* __restrict__ h2, const float* __restrict__ cnt, int N){
  int i = blockIdx.x*blockDim.x + threadIdx.x;
  if (i >= N*64) return;
  h2[i] = h2[i] / fmaxf(cnt[i >> 6], 1.f);
}

// ---------- fully fused set2set: one block (1024 thr = 16 waves) per graph ----------
__global__ __launch_bounds__(1024) void k_set2set(const float* __restrict__ x, const int* __restrict__ rb,
                          const float* __restrict__ T,
                          const float* __restrict__ b0, const float* __restrict__ b1,
                          float* __restrict__ xout){
  int b = blockIdx.x, j = threadIdx.x;
  int w = j >> 6, lane = j & 63;
  __shared__ float qstar[128], h0[64], c0[64], h1[64], c1[64];
  __shared__ float gs[256], wmax[16], wsum[16], racc[16][64];
  if (j < 128) qstar[j] = 0.f;
  if (j < 64){ h0[j] = 0.f; c0[j] = 0.f; h1[j] = 0.f; c1[j] = 0.f; }
  __syncthreads();
  int n0 = rb[b], n1 = rb[b+1];
  const float* T0 = T;            // wih0T [128][256]
  const float* T1 = T + 32768;    // whh0T [64][256]
  const float* T2 = T + 49152;    // wih1T [64][256]
  const float* T3 = T + 65536;    // whh1T [64][256]
  for (int s = 0; s < 5; ++s){
    if (j < 256){
      float a0 = b0[j], a1 = 0.f, a2 = 0.f, a3 = 0.f;
      #pragma unroll 4
      for (int k = 0; k < 128; k += 4){
        a0 = fmaf(T0[(k+0)*256 + j], qstar[k+0], a0);
        a1 = fmaf(T0[(k+1)*256 + j], qstar[k+1], a1);
        a2 = fmaf(T0[(k+2)*256 + j], qstar[k+2], a2);
        a3 = fmaf(T0[(k+3)*256 + j], qstar[k+3], a3);
      }
      #pragma unroll 4
      for (int k = 0; k < 64; k += 4){
        a0 = fmaf(T1[(k+0)*256 + j], h0[k+0], a0);
        a1 = fmaf(T1[(k+1)*256 + j], h0[k+1], a1);
        a2 = fmaf(T1[(k+2)*256 + j], h0[k+2], a2);
        a3 = fmaf(T1[(k+3)*256 + j], h0[k+3], a3);
      }
      gs[j] = (a0 + a1) + (a2 + a3);
    }
    __syncthreads();
    if (j < 64){
      float ig = sigf(gs[j]);
      float fg = sigf(gs[64+j]);
      float gg = tanhf(gs[128+j]);
      float og = sigf(gs[192+j]);
      float cn = fg*c0[j] + ig*gg;
      c0[j] = cn;
      h0[j] = og*tanhf(cn);
    }
    __syncthreads();
    if (j < 256){
      float a0 = b1[j], a1 = 0.f, a2 = 0.f, a3 = 0.f;
      #pragma unroll 4
      for (int k = 0; k < 64; k += 4){
        a0 = fmaf(T2[(k+0)*256 + j], h0[k+0], a0);
        a1 = fmaf(T2[(k+1)*256 + j], h0[k+1], a1);
        a2 = fmaf(T2[(k+2)*256 + j], h0[k+2], a2);
        a3 = fmaf(T2[(k+3)*256 + j], h0[k+3], a3);
      }
      #pragma unroll 4
      for (int k = 0; k < 64; k += 4){
        a0 = fmaf(T3[(k+0)*256 + j], h1[k+0], a0);
        a1 = fmaf(T3[(k+1)*256 + j], h1[k+1], a1);
        a2 = fmaf(T3[(k+2)*256 + j], h1[k+2], a2);
        a3 = fmaf(T3[(k+3)*256 + j], h1[k+3], a3);
      }
      gs[j] = (a0 + a1) + (a2 + a3);
    }
    __syncthreads();
    if (j < 64){
      float ig = sigf(gs[j]);
      float fg = sigf(gs[64+j]);
      float gg = tanhf(gs[128+j]);
      float og = sigf(gs[192+j]);
      float cn = fg*c1[j] + ig*gg;
      c1[j] = cn;
      float hn = og*tanhf(cn);
      h1[j] = hn;
      qstar[j] = hn;
    }
    __syncthreads();
    float lmax = -3.4e38f;
    for (int n = n0 + w; n < n1; n += 16){
      float v = x[(size_t)n*64 + lane]*qstar[lane];
      #pragma unroll
      for (int o = 32; o; o >>= 1) v += __shfl_xor(v, o);
      lmax = fmaxf(lmax, v);
    }
    if (lane == 0) wmax[w] = lmax;
    __syncthreads();
    float bmax = wmax[0];
    #pragma unroll
    for (int k = 1; k < 16; ++k) bmax = fmaxf(bmax, wmax[k]);
    float lsum = 0.f, lr = 0.f;
    for (int n = n0 + w; n < n1; n += 16){
      float xv = x[(size_t)n*64 + lane];
      float v = xv*qstar[lane];
      #pragma unroll
      for (int o = 32; o; o >>= 1) v += __shfl_xor(v, o);
      float wexp = expf(v - bmax);
      lsum += wexp;
      lr = fmaf(wexp, xv, lr);
    }
    if (lane == 0) wsum[w] = lsum;
    racc[w][lane] = lr;
    __syncthreads();
    if (j < 64){
      float r = 0.f, denom = 0.f;
      #pragma unroll
      for (int k = 0; k < 16; ++k){ r += racc[k][j]; denom += wsum[k]; }
      qstar[64 + j] = (denom > 0.f) ? (r/denom) : 0.f;
    }
    __syncthreads();
  }
  if (j < 128) xout[(size_t)b*128 + j] = qstar[j];
}

// ---------- head ----------
__global__ void k_concat(const float* __restrict__ x1, const float* __restrict__ x2,
                         float* __restrict__ z){
  int i = blockIdx.x*blockDim.x + threadIdx.x;
  if (i >= 256*256) return;
  int b = i >> 8, c = i & 255;
  z[i] = (c < 128) ? x1[b*128 + c] : x2[b*128 + (c - 128)];
}
__global__ void k_bn_par(float* __restrict__ X, const float* __restrict__ g,
                         const float* __restrict__ b, int F, int relu){
  int f = blockIdx.x, i = threadIdx.x;
  float v = X[(size_t)i*F + f];
  __shared__ float s1[256], s2[256];
  s1[i] = v; s2[i] = v*v;
  __syncthreads();
  for (int o = 128; o; o >>= 1){
    if (i < o){ s1[i] += s1[i+o]; s2[i] += s2[i+o]; }
    __syncthreads();
  }
  float mean = s1[0]*(1.f/256.f);
  float var  = s2[0]*(1.f/256.f) - mean*mean;
  float y = (v - mean)*rsqrtf(var + 1e-5f)*g[f] + b[f];
  if (relu) y = fmaxf(y, 0.f);
  X[(size_t)i*F + f] = y;
}
__global__ void k_fc(const float* __restrict__ X, const float* __restrict__ W,
                     const float* __restrict__ bias, float* __restrict__ Y, int K, int F){
  int b = blockIdx.x, f = threadIdx.x;
  if (f >= F) return;
  const float* xr = X + (size_t)b*K;
  const float* wr = W + (size_t)f*K;
  float acc = bias[f];
  for (int k = 0; k < K; ++k) acc = fmaf(xr[k], wr[k], acc);
  Y[(size_t)b*F + f] = acc;
}
__global__ void k_fc_out(const float* __restrict__ z2, const float* __restrict__ w,
                         const float* __restrict__ bias, float* __restrict__ out){
  int b = blockIdx.x*blockDim.x + threadIdx.x;
  if (b >= 256) return;
  float acc = bias[0];
  #pragma unroll
  for (int k = 0; k < 64; ++k) acc = fmaf(z2[b*64 + k], w[k], acc);
  out[b] = acc;
}

extern "C" void kernel_launch(void* const* d_in, const int* in_sizes, int n_in,
                              void* d_out, int out_size, void* d_ws, size_t ws_size,
                              hipStream_t stream) {
  const float* x_in     = (const float*)d_in[0];
  const float* edge_attr= (const float*)d_in[1];
  const float* conv_w   = (const float*)d_in[2];
  const float* conv_wih = (const float*)d_in[3];
  const float* conv_whh = (const float*)d_in[4];
  const float* conv_bih = (const float*)d_in[5];
  const float* conv_bhh = (const float*)d_in[6];
  const float* conv_nt  = (const float*)d_in[7];
  const float* s1_wih0 = (const float*)d_in[8];
  const float* s1_whh0 = (const float*)d_in[9];
  const float* s1_b0   = (const float*)d_in[10];
  const float* s1_wih1 = (const float*)d_in[11];
  const float* s1_whh1 = (const float*)d_in[12];
  const float* s1_b1   = (const float*)d_in[13];
  const float* s2_wih0 = (const float*)d_in[14];
  const float* s2_whh0 = (const float*)d_in[15];
  const float* s2_b0   = (const float*)d_in[16];
  const float* s2_wih1 = (const float*)d_in[17];
  const float* s2_whh1 = (const float*)d_in[18];
  const float* s2_b1   = (const float*)d_in[19];
  const float* bn_g    = (const float*)d_in[20];
  const float* bn_b    = (const float*)d_in[21];
  const float* prebn_g = (const float*)d_in[22];
  const float* prebn_b = (const float*)d_in[23];
  const float* fc_w0   = (const float*)d_in[24];
  const float* fc_b0   = (const float*)d_in[25];
  const float* fc_w1   = (const float*)d_in[26];
  const float* fc_b1   = (const float*)d_in[27];
  const float* fc_w2   = (const float*)d_in[28];
  const float* fc_b2   = (const float*)d_in[29];
  const float* fcbn_g0 = (const float*)d_in[30];
  const float* fcbn_b0 = (const float*)d_in[31];
  const float* fcbn_g1 = (const float*)d_in[32];
  const float* fcbn_b1 = (const float*)d_in[33];
  const int* edge_index   = (const int*)d_in[34];
  const int* node_type    = (const int*)d_in[35];
  const int* batch        = (const int*)d_in[36];
  const int* assign_src   = (const int*)d_in[37];
  const int* assign_dst   = (const int*)d_in[38];
  const int* edge_index_2 = (const int*)d_in[39];
  const int* batch_2      = (const int*)d_in[40];
  (void)in_sizes; (void)n_in; (void)out_size; (void)ws_size;

  // dynamic-LDS opt-ins (host-side, graph-capture-safe). 96/64KB proven r6/r8.
  int fused_ok = (hipFuncSetAttribute((const void*)k_gru_fused,
                    hipFuncAttributeMaxDynamicSharedMemorySize, 98304) == hipSuccess);
  int tr4s_ok = (hipFuncSetAttribute((const void*)k_tr4s,
                    hipFuncAttributeMaxDynamicSharedMemorySize, 65536) == hipSuccess);

  // ---- workspace layout ----
  float* Wp = (float*)d_ws;
  size_t o = 0;
  auto alloc = [&](size_t n){ float* p = Wp + o; o += n; return p; };
  float* h     = alloc((size_t)NN1*64);
  float* tr    = alloc((size_t)4*NN1*64);   // s[d][t][64] slabs; gi in GRU fallback
  float* aggr  = alloc((size_t)NN1*64);
  float* coeff = alloc(NN1);
  float* h2    = alloc((size_t)NN2*64);
  float* cnt   = alloc(NN2);
  float* x1    = alloc(256*128);
  float* x2    = alloc(256*128);
  float* z     = alloc(256*256);
  float* z1    = alloc(256*128);
  float* z2    = alloc(256*64);
  float* stats = alloc(128);
  float* w4    = alloc(245760);
  float* wihT  = alloc(61440);
  float* wihW  = alloc(61440);
  float* whh4  = alloc(61440);
  float* s2sT1 = alloc(81920);
  float* s2sT2 = alloc(81920);
  int* etype = (int*)alloc(EE1);
  int* cnt1  = (int*)alloc(NN1);
  int* R1    = (int*)alloc(NN1 + 1);
  int* ep1   = (int*)alloc(EE1);
  int* cnt2  = (int*)alloc(NN2);
  int* R2    = (int*)alloc(NN2 + 1);
  int* ep2   = (int*)alloc(EE2);
  int* csum  = (int*)alloc(260);
  int* rb1   = (int*)alloc(257);
  int* rb2   = (int*)alloc(257);

  const int* src1 = edge_index;
  const int* dst1 = edge_index + EE1;
  const int* src2 = edge_index_2;
  const int* dst2 = edge_index_2 + EE2;

  k_etype<<<(EE1+255)/256, 256, 0, stream>>>(edge_attr, etype, EE1);
  k_copy<<<(NN1*64+255)/256, 256, 0, stream>>>(x_in, h, NN1*64);
  k_prep_msgw<<<(245760+255)/256, 256, 0, stream>>>(conv_w, w4);
  k_prep_gruw<<<(61440+255)/256, 256, 0, stream>>>(conv_wih, conv_whh, wihT, wihW, whh4);
  k_s2strans<<<(81920+255)/256, 256, 0, stream>>>(s1_wih0, s1_whh0, s1_wih1, s1_whh1, s2sT1);
  k_s2strans<<<(81920+255)/256, 256, 0, stream>>>(s2_wih0, s2_whh0, s2_wih1, s2_whh1, s2sT2);
  k_batchptr<<<(NN1+255)/256, 256, 0, stream>>>(batch, rb1, NN1, 256);
  k_batchptr<<<(NN2+255)/256, 256, 0, stream>>>(batch_2, rb2, NN2, 256);

  {  // level-1 CSR (keys = dst; etype packed into edge payload)
    int M = NN1, nchunk = (M + 1023)/1024;
    hipMemsetAsync(cnt1, 0, (size_t)M*sizeof(int), stream);
    k_hist<<<(EE1+255)/256, 256, 0, stream>>>(dst1, cnt1, EE1);
    k_chunksum<<<nchunk, 256, 0, stream>>>(cnt1, csum, M);
    k_chunkscan<<<1, 256, 0, stream>>>(csum, nchunk);
    k_chunkapply<<<nchunk, 256, 0, stream>>>(cnt1, csum, R1, cnt1, M);
    k_scatter<<<(EE1+255)/256, 256, 0, stream>>>(src1, dst1, etype, cnt1, ep1, EE1);
  }
  {  // level-2 CSR
    int M = NN2, nchunk = (M + 1023)/1024;
    hipMemsetAsync(cnt2, 0, (size_t)M*sizeof(int), stream);
    k_hist<<<(EE2+255)/256, 256, 0, stream>>>(dst2, cnt2, EE2);
    k_chunksum<<<nchunk, 256, 0, stream>>>(cnt2, csum, M);
    k_chunkscan<<<1, 256, 0, stream>>>(csum, nchunk);
    k_chunkapply<<<nchunk, 256, 0, stream>>>(cnt2, csum, R2, cnt2, M);
    k_scatter<<<(EE2+255)/256, 256, 0, stream>>>(src2, dst2, nullptr, cnt2, ep2, EE2);
  }

  // GRU: fused (gi+gh+pointwise, 96KB LDS) or fallback (tr3 + finW)
  auto gru = [&](float* hbuf, int N, int lidx){
    if (fused_ok){
      k_gru_fused<<<256, 1024, 98304, stream>>>(aggr, hbuf,
          wihW + (size_t)lidx*12288, whh4 + (size_t)lidx*12288,
          conv_bih + lidx*192, conv_bhh + lidx*192, N);
    } else {
      k_tr3<<<768, 256, 0, stream>>>(aggr, wihT + (size_t)lidx*12288, tr, N);
      k_gru_finW<<<768, 256, 0, stream>>>(tr, hbuf, whh4 + (size_t)lidx*12288,
          conv_bih + lidx*192, conv_bhh + lidx*192, N);
    }
  };

  // ---- level-1: 3x MGGC(L=3) + BN + ReLU ----
  for (int i = 0; i < 3; ++i){
    k_coeff<<<(NN1+255)/256, 256, 0, stream>>>(conv_nt + i*9, node_type, coeff, NN1);
    for (int l = 0; l < 3; ++l){
      const float* W4l = w4 + (size_t)(i*3+l)*16384;   // 4 matrices, float4 layout
      // sweep-first: gather h (15MB hot) into s[d][t][64], then dense transform
      k_sweep4s<<<(NN1+3)/4, 256, 0, stream>>>(h, R1, ep1, coeff, tr, NN1);
      if (tr4s_ok){
        k_tr4s<<<512, 1024, 65536, stream>>>(tr, W4l, aggr, NN1);
      } else {
        for (int t = 0; t < 4; ++t)
          k_tr1s<<<1024, 256, 0, stream>>>(tr, W4l + (size_t)t*4096, aggr, NN1, t, t == 0);
      }
      gru(h, NN1, i);
    }
    hipMemsetAsync(stats, 0, 128*sizeof(float), stream);
    k_bnstats<<<256, 256, 0, stream>>>(h, stats, NN1);
    k_bnapply<<<(NN1*64+255)/256, 256, 0, stream>>>(h, stats, bn_g + i*64, bn_b + i*64, NN1, 1);
  }

  // ---- set2set (single fused kernel, 1024 threads/graph) ----
  k_set2set<<<256, 1024, 0, stream>>>(h, rb1, s2sT1, s1_b0, s1_b1, x1);

  // ---- avg_pool ----
  hipMemsetAsync(h2, 0, (size_t)NN2*64*sizeof(float), stream);
  hipMemsetAsync(cnt, 0, (size_t)NN2*sizeof(float), stream);
  k_pool_acc<<<(AA*64+255)/256, 256, 0, stream>>>(h, assign_src, assign_dst, h2, cnt, AA);
  k_pool_div<<<(NN2*64+255)/256, 256, 0, stream>>>(h2, cnt, NN2);

  // ---- level-2: 2x relu(MGGC(L=3)), only edge type 0 (transform->gather) ----
  for (int L = 3; L < 5; ++L){
    for (int l = 0; l < 3; ++l){
      const float* W4l = w4 + (size_t)(L*3+l)*16384;   // t=0 slice used
      k_tr1<<<1250, 256, 0, stream>>>(h2, W4l, nullptr, tr, NN2);
      k_sweep_p<<<(NN2+3)/4, 256, 0, stream>>>(tr, R2, ep2, aggr, NN2);
      gru(h2, NN2, L);
    }
    k_relu<<<(NN2*64+255)/256, 256, 0, stream>>>(h2, NN2*64);
  }

  k_set2set<<<256, 1024, 0, stream>>>(h2, rb2, s2sT2, s2_b0, s2_b1, x2);

  // ---- head ----
  k_concat<<<256, 256, 0, stream>>>(x1, x2, z);
  k_bn_par<<<256, 256, 0, stream>>>(z, prebn_g, prebn_b, 256, 0);
  k_fc<<<256, 128, 0, stream>>>(z, fc_w0, fc_b0, z1, 256, 128);
  k_bn_par<<<128, 256, 0, stream>>>(z1, fcbn_g0, fcbn_b0, 128, 1);
  k_fc<<<256, 64, 0, stream>>>(z1, fc_w1, fc_b1, z2, 128, 64);
  k_bn_par<<<64, 256, 0, stream>>>(z2, fcbn_g1, fcbn_b1, 64, 1);
  k_fc_out<<<4, 64, 0, stream>>>(z2, fc_w2, fc_b2, (float*)d_out);
}

// Round 10
// 2192.296 us; speedup vs baseline: 1.2915x; 1.2915x over previous
//
#include <hip/hip_runtime.h>

#define NN1 60000
#define EE1 600000
#define NN2 20000
#define EE2 150000
#define AA  60000

__device__ __forceinline__ float sigf(float x){ return 1.f/(1.f+expf(-x)); }
// wave-uniform broadcast of lane sl's value. sl may be a RUNTIME uniform
// (v_readlane_b32 takes an SGPR lane index), so loops need not unroll.
__device__ __forceinline__ float rlane(float v, int sl){
  return __int_as_float(__builtin_amdgcn_readlane(__float_as_int(v), sl));
}
// Broadcast 4 channels (ld.x..ld.w) of lane SL, then FMA into named scalars.
// ALL state is named scalars -> guaranteed VGPRs (rounds 1/3: arrays spill).
#define RL4(SL) hx = rlane(ld.x, SL); hy = rlane(ld.y, SL); hz = rlane(ld.z, SL); hw = rlane(ld.w, SL);
#define FMA4(A, W) A = fmaf(hx, W.x, A); A = fmaf(hy, W.y, A); A = fmaf(hz, W.z, A); A = fmaf(hw, W.w, A);

// ---------- elementwise ----------
__global__ void k_relu(float* a, int n){
  int i = blockIdx.x*blockDim.x + threadIdx.x;
  if (i < n) a[i] = fmaxf(a[i], 0.f);
}
__global__ void k_copy(const float* __restrict__ a, float* __restrict__ o, int n){
  int i = blockIdx.x*blockDim.x + threadIdx.x;
  if (i < n) o[i] = a[i];
}

// ---------- edge type ----------
__global__ void k_etype(const float* __restrict__ ea, int* __restrict__ etype, int E){
  int e = blockIdx.x*blockDim.x + threadIdx.x;
  if (e >= E) return;
  const float* p = ea + (size_t)e*10;
  float best = p[0]; int bi = 0;
  #pragma unroll
  for (int k = 1; k < 4; ++k){ float v = p[k]; if (v > best){ best = v; bi = k; } }
  etype[e] = bi;
}

__global__ void k_coeff(const float* __restrict__ nt, const int* __restrict__ node_type,
                        float* __restrict__ coeff, int N){
  int n = blockIdx.x*blockDim.x + threadIdx.x;
  if (n < N) coeff[n] = nt[node_type[n]];
}

// ---------- batch row pointers (batch sorted ascending) ----------
__global__ void k_batchptr(const int* __restrict__ batch, int* __restrict__ rb, int N, int B){
  int n = blockIdx.x*blockDim.x + threadIdx.x;
  if (n >= N) return;
  int b = batch[n];
  if (n == 0){ for (int g = 0; g <= b; ++g) rb[g] = 0; }
  else {
    int pb = batch[n-1];
    for (int g = pb+1; g <= b; ++g) rb[g] = n;
  }
  if (n == N-1){ for (int g = b+1; g <= B; ++g) rb[g] = N; }
}

// ---------- weight prep ----------
// msg weights: conv_w[m][c][d] (m = (li*3+l)*4+t) -> w4[m][c4][d][q],
// float4 element (c4,d) = { W[4c4+0][d], W[4c4+1][d], W[4c4+2][d], W[4c4+3][d] }.
// In-kernel lane d reads float4 index c4*64+d: contiguous -> conflict-free b128.
__global__ void k_prep_msgw(const float* __restrict__ w, float* __restrict__ w4){
  int idx = blockIdx.x*256 + threadIdx.x;   // 60*4096 = 245760
  if (idx >= 245760) return;
  int m = idx >> 12, r = idx & 4095;
  int c4 = r >> 8, d = (r >> 2) & 63, q = r & 3;
  w4[idx] = w[m*4096 + (4*c4+q)*64 + d];
}
// GRU weights, three layouts:
//  wihT[l][t][c4][d][q] = wih[l][(64t+d)][4c4+q]  (tr3 fallback: lane d owns row 64t+d)
//  wihW[l][c4][j][q]    = wih[l][j][4c4+q]        (fused: lane l owns rows {l,64+l,128+l})
//  whh4[l][c4][j][q]    = whh[l][j][4c4+q]
__global__ void k_prep_gruw(const float* __restrict__ wih, const float* __restrict__ whh,
                            float* __restrict__ wihT, float* __restrict__ wihW,
                            float* __restrict__ whh4){
  int idx = blockIdx.x*256 + threadIdx.x;   // 5*12288 = 61440 each
  if (idx >= 61440) return;
  {
    int l = idx / 12288, r = idx % 12288;
    int t = r >> 12, rr = r & 4095;
    int c4 = rr >> 8, d = (rr >> 2) & 63, q = rr & 3;
    wihT[idx] = wih[l*12288 + (64*t + d)*64 + 4*c4 + q];
  }
  {
    int l = idx / 12288, rr = idx % 12288;
    int e = rr >> 2, q = rr & 3;
    int c4 = e / 192, j = e - c4*192;
    wihW[idx] = wih[l*12288 + j*64 + 4*c4 + q];
    whh4[idx] = whh[l*12288 + j*64 + 4*c4 + q];
  }
}

// ---------- set2set LSTM weight transpose to [k][j] (coalesced over gate row j) ----------
__global__ void k_s2strans(const float* __restrict__ wih0, const float* __restrict__ whh0,
                           const float* __restrict__ wih1, const float* __restrict__ whh1,
                           float* __restrict__ T){
  int idx = blockIdx.x*256 + threadIdx.x;
  if (idx < 32768){ int k = idx >> 8, j = idx & 255; T[idx] = wih0[j*128 + k]; }
  else if (idx < 49152){ int r = idx - 32768; int k = r >> 8, j = r & 255; T[idx] = whh0[j*64 + k]; }
  else if (idx < 65536){ int r = idx - 49152; int k = r >> 8, j = r & 255; T[idx] = wih1[j*64 + k]; }
  else if (idx < 81920){ int r = idx - 65536; int k = r >> 8, j = r & 255; T[idx] = whh1[j*64 + k]; }
}

// ---------- CSR build ----------
__global__ void k_hist(const int* __restrict__ dst, int* __restrict__ cnt, int E){
  int e = blockIdx.x*blockDim.x + threadIdx.x;
  if (e >= E) return;
  atomicAdd(&cnt[dst[e]], 1);
}
__global__ void k_chunksum(const int* __restrict__ cnt, int* __restrict__ csum, int M){
  __shared__ int sh[256];
  int base = blockIdx.x*1024;
  int s = 0;
  for (int i = threadIdx.x; i < 1024; i += 256){
    int idx = base + i;
    if (idx < M) s += cnt[idx];
  }
  sh[threadIdx.x] = s;
  __syncthreads();
  for (int o = 128; o; o >>= 1){
    if (threadIdx.x < o) sh[threadIdx.x] += sh[threadIdx.x + o];
    __syncthreads();
  }
  if (threadIdx.x == 0) csum[blockIdx.x] = sh[0];
}
__global__ void k_chunkscan(int* __restrict__ csum, int nchunk){
  __shared__ int sh[256];
  int i = threadIdx.x;
  int v = (i < nchunk) ? csum[i] : 0;
  sh[i] = v; __syncthreads();
  for (int o = 1; o < 256; o <<= 1){
    int y = (i >= o) ? sh[i-o] : 0;
    __syncthreads();
    sh[i] += y;
    __syncthreads();
  }
  if (i < nchunk) csum[i] = sh[i] - v;
  if (i == 255) csum[nchunk] = sh[255];
}
__global__ void k_chunkapply(const int* __restrict__ cnt, const int* __restrict__ csum,
                             int* __restrict__ R, int* __restrict__ cur, int M){
  __shared__ int sh[256];
  int base = blockIdx.x*1024;
  int i0 = base + threadIdx.x*4;
  int v[4]; int s = 0;
  #pragma unroll
  for (int k = 0; k < 4; ++k){ int idx = i0 + k; v[k] = (idx < M) ? cnt[idx] : 0; s += v[k]; }
  sh[threadIdx.x] = s; __syncthreads();
  for (int o = 1; o < 256; o <<= 1){
    int y = (threadIdx.x >= o) ? sh[threadIdx.x-o] : 0;
    __syncthreads();
    sh[threadIdx.x] += y;
    __syncthreads();
  }
  int run = csum[blockIdx.x] + sh[threadIdx.x] - s;
  #pragma unroll
  for (int k = 0; k < 4; ++k){
    int idx = i0 + k;
    if (idx < M){ R[idx] = run; cur[idx] = run; run += v[k]; }
  }
  if (threadIdx.x == 255 && base + 1024 >= M) R[M] = csum[blockIdx.x] + sh[255];
}
// scatter packs the FULL tr row index (t*N + src, < 2^31) so the sweep's
// per-edge address math is a single shift (r10: was 64-bit mul + mask/shift).
__global__ void k_scatter(const int* __restrict__ src, const int* __restrict__ dst,
                          const int* __restrict__ etype, int* __restrict__ cur,
                          int* __restrict__ ep, int E, int N){
  int e = blockIdx.x*blockDim.x + threadIdx.x;
  if (e >= E) return;
  int t = etype ? etype[e] : 0;
  int pos = atomicAdd(&cur[dst[e]], 1);
  ep[pos] = t*N + src[e];
}

// ---------- dense transforms: LDS weights + 1 coalesced load + readlane ----------
// tr[t][n][d] = coeff[n] * sum_c h[n][c]*W[t][c][d].
// Per 4-node group: ONE dwordx4/wave; readlane broadcasts; NAMED-SCALAR
// accumulators (arrays spill: r1/r3). Weights in LDS, conflict-free b128.

// 4 matrices in one pass: 64 KB LDS, 1024 thr, rl:fma = 1:4.  [r8: -440us]
__global__ __launch_bounds__(1024, 4) void k_tr4d(
    const float* __restrict__ h, const float* __restrict__ W4,
    const float* __restrict__ coeff, float* __restrict__ tr, int N){
  extern __shared__ float4 wl[];           // [4][1024] = 64 KB
  for (int i = threadIdx.x; i < 4096; i += 1024) wl[i] = ((const float4*)W4)[i];
  __syncthreads();
  int lane = threadIdx.x & 63, wv = threadIdx.x >> 6;   // 16 waves
  int ng = N >> 2, stride = gridDim.x*16;
  for (int g = blockIdx.x*16 + wv; g < ng; g += stride){
    int n0 = g << 2;
    float4 ld = ((const float4*)(h + ((size_t)n0 << 6)))[lane];
    float a00=0.f,a01=0.f,a02=0.f,a03=0.f;
    float a10=0.f,a11=0.f,a12=0.f,a13=0.f;
    float a20=0.f,a21=0.f,a22=0.f,a23=0.f;
    float a30=0.f,a31=0.f,a32=0.f,a33=0.f;
    for (int c4 = 0; c4 < 16; ++c4){
      int wb = (c4 << 6) + lane;
      float4 w0 = wl[wb], w1 = wl[1024+wb], w2 = wl[2048+wb], w3 = wl[3072+wb];
      float hx, hy, hz, hw;
      RL4(c4)     FMA4(a00,w0) FMA4(a10,w1) FMA4(a20,w2) FMA4(a30,w3)
      RL4(16|c4)  FMA4(a01,w0) FMA4(a11,w1) FMA4(a21,w2) FMA4(a31,w3)
      RL4(32|c4)  FMA4(a02,w0) FMA4(a12,w1) FMA4(a22,w2) FMA4(a32,w3)
      RL4(48|c4)  FMA4(a03,w0) FMA4(a13,w1) FMA4(a23,w2) FMA4(a33,w3)
    }
    float4 cv = ((const float4*)coeff)[g];
    a00*=cv.x; a01*=cv.y; a02*=cv.z; a03*=cv.w;
    a10*=cv.x; a11*=cv.y; a12*=cv.z; a13*=cv.w;
    a20*=cv.x; a21*=cv.y; a22*=cv.z; a23*=cv.w;
    a30*=cv.x; a31*=cv.y; a32*=cv.z; a33*=cv.w;
    float* o0 = tr + ((size_t)n0 << 6) + lane;
    o0[0]=a00; o0[64]=a01; o0[128]=a02; o0[192]=a03;
    float* o1 = tr + (((size_t)N + n0) << 6) + lane;
    o1[0]=a10; o1[64]=a11; o1[128]=a12; o1[192]=a13;
    float* o2 = tr + (((size_t)2*N + n0) << 6) + lane;
    o2[0]=a20; o2[64]=a21; o2[128]=a22; o2[192]=a23;
    float* o3 = tr + (((size_t)3*N + n0) << 6) + lane;
    o3[0]=a30; o3[64]=a31; o3[128]=a32; o3[192]=a33;
  }
}

// single-matrix variant (level-2; also tr4d fallback), 16 KB static LDS
__global__ __launch_bounds__(256) void k_tr1(
    const float* __restrict__ h, const float* __restrict__ W4,
    const float* __restrict__ coeff, float* __restrict__ tr, int N){
  __shared__ float4 wl[1024];                 // 16 KB
  for (int i = threadIdx.x; i < 1024; i += 256) wl[i] = ((const float4*)W4)[i];
  __syncthreads();
  int lane = threadIdx.x & 63, w = threadIdx.x >> 6;
  int ng = N >> 2, stride = gridDim.x*4;
  for (int g = blockIdx.x*4 + w; g < ng; g += stride){
    int n0 = g << 2;
    float4 ld = ((const float4*)(h + ((size_t)n0 << 6)))[lane];
    float a0=0.f, a1=0.f, a2=0.f, a3=0.f;
    for (int c4 = 0; c4 < 16; ++c4){
      float4 w0 = wl[(c4 << 6) + lane];
      float hx, hy, hz, hw;
      RL4(c4)       FMA4(a0, w0)
      RL4(16|c4)    FMA4(a1, w0)
      RL4(32|c4)    FMA4(a2, w0)
      RL4(48|c4)    FMA4(a3, w0)
    }
    if (coeff){
      float4 cv = ((const float4*)coeff)[g];
      a0 *= cv.x; a1 *= cv.y; a2 *= cv.z; a3 *= cv.w;
    }
    float* o0 = tr + ((size_t)n0 << 6) + lane;
    o0[0] = a0; o0[64] = a1; o0[128] = a2; o0[192] = a3;
  }
}

// ---------- merged sweep (gather tr rows per dst via CSR) ----------
// r10: ep holds the packed row index (t*N+src) -> addr = (ridx<<6)+lane.
// 4-unroll with 4 independent accumulators: breaks the serial fp-add chain
// and puts 4 gathers in flight per wave (was 1 load per ~20cy, 1.9TB/s).
__global__ void k_sweep_p(const float* __restrict__ tr, const int* __restrict__ R,
                          const int* __restrict__ ep, float* __restrict__ aggr, int N){
  int w = threadIdx.x >> 6, lane = threadIdx.x & 63;
  int d = blockIdx.x*4 + w;
  if (d >= N) return;
  int p = R[d], pend = R[d+1];
  float a0=0.f, a1=0.f, a2=0.f, a3=0.f;
  while (p < pend){
    int m = pend - p; if (m > 64) m = 64;
    int ev = (lane < m) ? ep[p + lane] : 0;
    int j = 0;
    for (; j + 4 <= m; j += 4){
      int r0 = __shfl(ev, j),   r1 = __shfl(ev, j+1);
      int r2 = __shfl(ev, j+2), r3 = __shfl(ev, j+3);
      float v0 = tr[((size_t)r0 << 6) + lane];
      float v1 = tr[((size_t)r1 << 6) + lane];
      float v2 = tr[((size_t)r2 << 6) + lane];
      float v3 = tr[((size_t)r3 << 6) + lane];
      a0 += v0; a1 += v1; a2 += v2; a3 += v3;
    }
    for (; j < m; ++j){
      int r0 = __shfl(ev, j);
      a0 += tr[((size_t)r0 << 6) + lane];
    }
    p += m;
  }
  aggr[(size_t)d*64 + lane] = (a0 + a1) + (a2 + a3);
}

// ---------- tr3: GRU-fallback gi transform (LDS weights + readlane) ----------
__global__ __launch_bounds__(256) void k_tr3(
    const float* __restrict__ h, const float* __restrict__ W4,
    float* __restrict__ tr, int N){
  __shared__ float4 wl[3072];                 // 48 KB (3 matrices)
  for (int i = threadIdx.x; i < 3072; i += 256) wl[i] = ((const float4*)W4)[i];
  __syncthreads();
  int lane = threadIdx.x & 63, w = threadIdx.x >> 6;
  int ng = N >> 2, stride = gridDim.x*4;
  for (int g = blockIdx.x*4 + w; g < ng; g += stride){
    int n0 = g << 2;
    float4 ld = ((const float4*)(h + ((size_t)n0 << 6)))[lane];
    float a00=0.f,a01=0.f,a02=0.f,a03=0.f;
    float a10=0.f,a11=0.f,a12=0.f,a13=0.f;
    float a20=0.f,a21=0.f,a22=0.f,a23=0.f;
    for (int c4 = 0; c4 < 16; ++c4){
      float4 w0 = wl[(c4 << 6) + lane];
      float4 w1 = wl[1024 + (c4 << 6) + lane];
      float4 w2 = wl[2048 + (c4 << 6) + lane];
      float hx, hy, hz, hw;
      RL4(c4)       FMA4(a00, w0) FMA4(a10, w1) FMA4(a20, w2)
      RL4(16|c4)    FMA4(a01, w0) FMA4(a11, w1) FMA4(a21, w2)
      RL4(32|c4)    FMA4(a02, w0) FMA4(a12, w1) FMA4(a22, w2)
      RL4(48|c4)    FMA4(a03, w0) FMA4(a13, w1) FMA4(a23, w2)
    }
    float* o0 = tr + ((size_t)n0 << 6) + lane;
    o0[0] = a00; o0[64] = a01; o0[128] = a02; o0[192] = a03;
    float* o1 = tr + (((size_t)N + n0) << 6) + lane;
    o1[0] = a10; o1[64] = a11; o1[128] = a12; o1[192] = a13;
    float* o2 = tr + (((size_t)2*N + n0) << 6) + lane;
    o2[0] = a20; o2[64] = a21; o2[128] = a22; o2[192] = a23;
  }
}

// ---------- fully fused GRU: both GEMVs + pointwise in ONE kernel ----------
// wih AND whh in LDS (96KB, 1 block/CU, 16 waves = 4/SIMD). GRU algebra folds
// gi_r+gh_r and gi_z+gh_z into single accumulators. Per 4-node group: 2
// coalesced dwordx4 loads, 96 conflict-free ds_read_b128, 512 rl + 1536 fma,
// in-lane pointwise, ZERO barriers in the loop.  [round 6: -950us]
#define RLAH(SL) \
  ax = rlane(la.x, SL); ay = rlane(la.y, SL); az2 = rlane(la.z, SL); aw = rlane(la.w, SL); \
  hx = rlane(ld.x, SL); hy = rlane(ld.y, SL); hz  = rlane(ld.z, SL); hw = rlane(ld.w, SL);
#define GACC(SL, R, Z, P, Q) RLAH(SL) \
  R = fmaf(ax,iwr.x,R); R = fmaf(ay,iwr.y,R); R = fmaf(az2,iwr.z,R); R = fmaf(aw,iwr.w,R); \
  R = fmaf(hx,hwr.x,R); R = fmaf(hy,hwr.y,R); R = fmaf(hz,hwr.z,R);  R = fmaf(hw,hwr.w,R); \
  Z = fmaf(ax,iwz.x,Z); Z = fmaf(ay,iwz.y,Z); Z = fmaf(az2,iwz.z,Z); Z = fmaf(aw,iwz.w,Z); \
  Z = fmaf(hx,hwz.x,Z); Z = fmaf(hy,hwz.y,Z); Z = fmaf(hz,hwz.z,Z);  Z = fmaf(hw,hwz.w,Z); \
  P = fmaf(ax,iwn.x,P); P = fmaf(ay,iwn.y,P); P = fmaf(az2,iwn.z,P); P = fmaf(aw,iwn.w,P); \
  Q = fmaf(hx,hwn.x,Q); Q = fmaf(hy,hwn.y,Q); Q = fmaf(hz,hwn.z,Q);  Q = fmaf(hw,hwn.w,Q);
#define GFIN(K, R, Z, P, Q) { \
    size_t off = base + ((size_t)(K) << 6) + lane; \
    float hv = h[off]; \
    float r = sigf(R), z = sigf(Z); \
    float nn = tanhf(P + r*Q); \
    h[off] = (1.f - z)*nn + z*hv; }
__global__ __launch_bounds__(1024, 4) void k_gru_fused(
    const float* __restrict__ aggr, float* __restrict__ h,
    const float* __restrict__ wihW, const float* __restrict__ whhW,
    const float* __restrict__ bih, const float* __restrict__ bhh, int N){
  extern __shared__ float4 wl[];           // [6144]: wih | whh, 96 KB
  for (int i = threadIdx.x; i < 6144; i += 1024)
    wl[i] = (i < 3072) ? ((const float4*)wihW)[i] : ((const float4*)whhW)[i - 3072];
  __syncthreads();
  const float4* wi = wl;
  const float4* wh = wl + 3072;
  int lane = threadIdx.x & 63, wv = threadIdx.x >> 6;
  float br  = bih[lane]     + bhh[lane];
  float bz  = bih[64+lane]  + bhh[64+lane];
  float bp  = bih[128+lane];                // gi_n bias
  float bq  = bhh[128+lane];                // gh_n bias
  int ng = N >> 2, stride = gridDim.x*16;
  for (int g = blockIdx.x*16 + wv; g < ng; g += stride){
    int n0 = g << 2;
    size_t base = (size_t)n0 << 6;
    float4 la = ((const float4*)(aggr + base))[lane];
    float4 ld = ((const float4*)(h + base))[lane];
    float r0=br, r1=br, r2=br, r3=br;
    float z0=bz, z1=bz, z2=bz, z3=bz;
    float p0=bp, p1=bp, p2=bp, p3=bp;
    float q0=bq, q1=bq, q2=bq, q3=bq;
    for (int c4 = 0; c4 < 16; ++c4){
      int wb = c4*192 + lane;
      float4 iwr = wi[wb], iwz = wi[wb+64], iwn = wi[wb+128];
      float4 hwr = wh[wb], hwz = wh[wb+64], hwn = wh[wb+128];
      float ax, ay, az2, aw, hx, hy, hz, hw;
      GACC(c4,    r0, z0, p0, q0)
      GACC(16|c4, r1, z1, p1, q1)
      GACC(32|c4, r2, z2, p2, q2)
      GACC(48|c4, r3, z3, p3, q3)
    }
    GFIN(0, r0, z0, p0, q0)
    GFIN(1, r1, z1, p1, q1)
    GFIN(2, r2, z2, p2, q2)
    GFIN(3, r3, z3, p3, q3)
  }
}

// ---------- GRU finalize fallback (used only if 96KB dynamic LDS refused) ----------
#define GRUACC(SL, RK, ZK, NK) RL4(SL) FMA4(RK, wr) FMA4(ZK, wz) FMA4(NK, wn)
#define GRUFIN(K, RK, ZK, NK) { \
    size_t off = base + (K << 6) + lane; \
    float gir = gi[off], giz = gi[S + off], gin = gi[2*S + off]; \
    float hv = h[off]; \
    float r = sigf(gir + bir + RK); \
    float z = sigf(giz + biz + ZK); \
    float nv = tanhf(gin + bin_ + r*NK); \
    h[off] = (1.f - z)*nv + z*hv; }
__global__ __launch_bounds__(256, 3) void k_gru_finW(
    const float* __restrict__ gi, float* __restrict__ h,
    const float* __restrict__ whh4,
    const float* __restrict__ bih, const float* __restrict__ bhh, int N){
  __shared__ float4 wh[3072];              // [c4][192] = whh[j][4c4+q], 48KB
  for (int i = threadIdx.x; i < 3072; i += 256) wh[i] = ((const float4*)whh4)[i];
  __syncthreads();
  int lane = threadIdx.x & 63, w = threadIdx.x >> 6;
  float bir = bih[lane], biz = bih[64+lane], bin_ = bih[128+lane];
  float bhr = bhh[lane], bhz = bhh[64+lane], bhn = bhh[128+lane];
  size_t S = (size_t)N << 6;
  int ng = N >> 2, stride = gridDim.x*4;
  for (int g = blockIdx.x*4 + w; g < ng; g += stride){
    int n0 = g << 2;
    size_t base = (size_t)n0 << 6;
    float4 ld = ((const float4*)(h + base))[lane];
    float ar0=bhr, ar1=bhr, ar2=bhr, ar3=bhr;
    float az0=bhz, az1=bhz, az2=bhz, az3=bhz;
    float an0=bhn, an1=bhn, an2=bhn, an3=bhn;
    for (int c4 = 0; c4 < 16; ++c4){
      int wb = c4*192 + lane;
      float4 wr = wh[wb];
      float4 wz = wh[wb + 64];
      float4 wn = wh[wb + 128];
      float hx, hy, hz, hw;
      GRUACC(c4,    ar0, az0, an0)
      GRUACC(16|c4, ar1, az1, an1)
      GRUACC(32|c4, ar2, az2, an2)
      GRUACC(48|c4, ar3, az3, an3)
    }
    GRUFIN(0, ar0, az0, an0)
    GRUFIN(1, ar1, az1, an1)
    GRUFIN(2, ar2, az2, an2)
    GRUFIN(3, ar3, az3, an3)
  }
}

// ---------- batch norm over nodes ----------
__global__ void k_bnstats(const float* __restrict__ h, float* __restrict__ stats, int N){
  int c = threadIdx.x & 63;
  int g = threadIdx.x >> 6;
  float s = 0.f, s2 = 0.f;
  for (int n = blockIdx.x*4 + g; n < N; n += gridDim.x*4){
    float v = h[(size_t)n*64 + c]; s += v; s2 += v*v;
  }
  __shared__ float sh[4][64], sh2[4][64];
  sh[g][c] = s; sh2[g][c] = s2;
  __syncthreads();
  if (g == 0){
    float ts = sh[0][c]+sh[1][c]+sh[2][c]+sh[3][c];
    float t2 = sh2[0][c]+sh2[1][c]+sh2[2][c]+sh2[3][c];
    atomicAdd(&stats[c], ts); atomicAdd(&stats[64+c], t2);
  }
}
__global__ void k_bnapply(float* __restrict__ h, const float* __restrict__ stats,
                          const float* __restrict__ g, const float* __restrict__ b,
                          int N, int relu){
  int i = blockIdx.x*blockDim.x + threadIdx.x;
  if (i >= N*64) return;
  int c = i & 63;
  float inv = 1.f/(float)N;
  float mean = stats[c]*inv;
  float var  = stats[64+c]*inv - mean*mean;
  float y = (h[i]-mean)*rsqrtf(var + 1e-5f)*g[c] + b[c];
  if (relu) y = fmaxf(y, 0.f);
  h[i] = y;
}

// ---------- avg_pool ----------
__global__ void k_pool_acc(const float* __restrict__ h, const int* __restrict__ asrc,
                           const int* __restrict__ adst, float* __restrict__ h2,
                           float* __restrict__ cnt, int A){
  int i = blockIdx.x*blockDim.x + threadIdx.x;
  if (i >= A*64) return;
  int a = i >> 6, c = i & 63;
  int s = asrc[a], d = adst[a];
  atomicAdd(&h2[(size_t)d*64 + c], h[(size_t)s*64 + c]);
  if (c == 0) atomicAdd(&cnt[d], 1.f);
}
__global__ void k_pool_div(float* __restrict__ h2, const float* __restrict__ cnt, int N){
  int i = blockIdx.x*blockDim.x + threadIdx.x;
  if (i >= N*64) return;
  h2[i] = h2[i] / fmaxf(cnt[i >> 6], 1.f);
}

// ---------- fully fused set2set: one block (1024 thr = 16 waves) per graph ----------
// r10: ONLINE softmax attention — single pass over x per step (was max pass +
// sum pass = 10 x-reads/call; now 5). Wave partials (wmax,wsum,racc) combined
// exactly via exp(wmax-M) scaling.
__global__ __launch_bounds__(1024) void k_set2set(const float* __restrict__ x, const int* __restrict__ rb,
                          const float* __restrict__ T,
                          const float* __restrict__ b0, const float* __restrict__ b1,
                          float* __restrict__ xout){
  int b = blockIdx.x, j = threadIdx.x;
  int w = j >> 6, lane = j & 63;
  __shared__ float qstar[128], h0[64], c0[64], h1[64], c1[64];
  __shared__ float gs[256], wmax[16], wsum[16], racc[16][64];
  if (j < 128) qstar[j] = 0.f;
  if (j < 64){ h0[j] = 0.f; c0[j] = 0.f; h1[j] = 0.f; c1[j] = 0.f; }
  __syncthreads();
  int n0 = rb[b], n1 = rb[b+1];
  const float* T0 = T;            // wih0T [128][256]
  const float* T1 = T + 32768;    // whh0T [64][256]
  const float* T2 = T + 49152;    // wih1T [64][256]
  const float* T3 = T + 65536;    // whh1T [64][256]
  for (int s = 0; s < 5; ++s){
    if (j < 256){
      float a0 = b0[j], a1 = 0.f, a2 = 0.f, a3 = 0.f;
      #pragma unroll 4
      for (int k = 0; k < 128; k += 4){
        a0 = fmaf(T0[(k+0)*256 + j], qstar[k+0], a0);
        a1 = fmaf(T0[(k+1)*256 + j], qstar[k+1], a1);
        a2 = fmaf(T0[(k+2)*256 + j], qstar[k+2], a2);
        a3 = fmaf(T0[(k+3)*256 + j], qstar[k+3], a3);
      }
      #pragma unroll 4
      for (int k = 0; k < 64; k += 4){
        a0 = fmaf(T1[(k+0)*256 + j], h0[k+0], a0);
        a1 = fmaf(T1[(k+1)*256 + j], h0[k+1], a1);
        a2 = fmaf(T1[(k+2)*256 + j], h0[k+2], a2);
        a3 = fmaf(T1[(k+3)*256 + j], h0[k+3], a3);
      }
      gs[j] = (a0 + a1) + (a2 + a3);
    }
    __syncthreads();
    if (j < 64){
      float ig = sigf(gs[j]);
      float fg = sigf(gs[64+j]);
      float gg = tanhf(gs[128+j]);
      float og = sigf(gs[192+j]);
      float cn = fg*c0[j] + ig*gg;
      c0[j] = cn;
      h0[j] = og*tanhf(cn);
    }
    __syncthreads();
    if (j < 256){
      float a0 = b1[j], a1 = 0.f, a2 = 0.f, a3 = 0.f;
      #pragma unroll 4
      for (int k = 0; k < 64; k += 4){
        a0 = fmaf(T2[(k+0)*256 + j], h0[k+0], a0);
        a1 = fmaf(T2[(k+1)*256 + j], h0[k+1], a1);
        a2 = fmaf(T2[(k+2)*256 + j], h0[k+2], a2);
        a3 = fmaf(T2[(k+3)*256 + j], h0[k+3], a3);
      }
      #pragma unroll 4
      for (int k = 0; k < 64; k += 4){
        a0 = fmaf(T3[(k+0)*256 + j], h1[k+0], a0);
        a1 = fmaf(T3[(k+1)*256 + j], h1[k+1], a1);
        a2 = fmaf(T3[(k+2)*256 + j], h1[k+2], a2);
        a3 = fmaf(T3[(k+3)*256 + j], h1[k+3], a3);
      }
      gs[j] = (a0 + a1) + (a2 + a3);
    }
    __syncthreads();
    if (j < 64){
      float ig = sigf(gs[j]);
      float fg = sigf(gs[64+j]);
      float gg = tanhf(gs[128+j]);
      float og = sigf(gs[192+j]);
      float cn = fg*c1[j] + ig*gg;
      c1[j] = cn;
      float hn = og*tanhf(cn);
      h1[j] = hn;
      qstar[j] = hn;
    }
    __syncthreads();
    // ---- online-softmax attention: ONE pass over the graph's nodes ----
    float lmax = -3.4e38f, lsum = 0.f, lr = 0.f;
    for (int n = n0 + w; n < n1; n += 16){
      float xv = x[(size_t)n*64 + lane];
      float v = xv*qstar[lane];
      #pragma unroll
      for (int o = 32; o; o >>= 1) v += __shfl_xor(v, o);
      float nm = fmaxf(lmax, v);
      float corr = expf(lmax - nm);    // 0 on first node (lmax=-inf-ish)
      float e = expf(v - nm);
      lsum = fmaf(lsum, corr, e);
      lr   = fmaf(lr, corr, e*xv);
      lmax = nm;
    }
    if (lane == 0){ wmax[w] = lmax; wsum[w] = lsum; }
    racc[w][lane] = lr;
    __syncthreads();
    if (j < 64){
      float M = wmax[0];
      #pragma unroll
      for (int k = 1; k < 16; ++k) M = fmaxf(M, wmax[k]);
      float denom = 0.f, r = 0.f;
      #pragma unroll
      for (int k = 0; k < 16; ++k){
        float sc = expf(wmax[k] - M);  // 0 for empty waves
        denom = fmaf(wsum[k], sc, denom);
        r     = fmaf(racc[k][j], sc, r);
      }
      qstar[64 + j] = (denom > 0.f) ? (r/denom) : 0.f;
    }
    __syncthreads();
  }
  if (j < 128) xout[(size_t)b*128 + j] = qstar[j];
}

// ---------- head ----------
__global__ void k_concat(const float* __restrict__ x1, const float* __restrict__ x2,
                         float* __restrict__ z){
  int i = blockIdx.x*blockDim.x + threadIdx.x;
  if (i >= 256*256) return;
  int b = i >> 8, c = i & 255;
  z[i] = (c < 128) ? x1[b*128 + c] : x2[b*128 + (c - 128)];
}
__global__ void k_bn_par(float* __restrict__ X, const float* __restrict__ g,
                         const float* __restrict__ b, int F, int relu){
  int f = blockIdx.x, i = threadIdx.x;
  float v = X[(size_t)i*F + f];
  __shared__ float s1[256], s2[256];
  s1[i] = v; s2[i] = v*v;
  __syncthreads();
  for (int o = 128; o; o >>= 1){
    if (i < o){ s1[i] += s1[i+o]; s2[i] += s2[i+o]; }
    __syncthreads();
  }
  float mean = s1[0]*(1.f/256.f);
  float var  = s2[0]*(1.f/256.f) - mean*mean;
  float y = (v - mean)*rsqrtf(var + 1e-5f)*g[f] + b[f];
  if (relu) y = fmaxf(y, 0.f);
  X[(size_t)i*F + f] = y;
}
__global__ void k_fc(const float* __restrict__ X, const float* __restrict__ W,
                     const float* __restrict__ bias, float* __restrict__ Y, int K, int F){
  int b = blockIdx.x, f = threadIdx.x;
  if (f >= F) return;
  const float* xr = X + (size_t)b*K;
  const float* wr = W + (size_t)f*K;
  float acc = bias[f];
  for (int k = 0; k < K; ++k) acc = fmaf(xr[k], wr[k], acc);
  Y[(size_t)b*F + f] = acc;
}
__global__ void k_fc_out(const float* __restrict__ z2, const float* __restrict__ w,
                         const float* __restrict__ bias, float* __restrict__ out){
  int b = blockIdx.x*blockDim.x + threadIdx.x;
  if (b >= 256) return;
  float acc = bias[0];
  #pragma unroll
  for (int k = 0; k < 64; ++k) acc = fmaf(z2[b*64 + k], w[k], acc);
  out[b] = acc;
}

extern "C" void kernel_launch(void* const* d_in, const int* in_sizes, int n_in,
                              void* d_out, int out_size, void* d_ws, size_t ws_size,
                              hipStream_t stream) {
  const float* x_in     = (const float*)d_in[0];
  const float* edge_attr= (const float*)d_in[1];
  const float* conv_w   = (const float*)d_in[2];
  const float* conv_wih = (const float*)d_in[3];
  const float* conv_whh = (const float*)d_in[4];
  const float* conv_bih = (const float*)d_in[5];
  const float* conv_bhh = (const float*)d_in[6];
  const float* conv_nt  = (const float*)d_in[7];
  const float* s1_wih0 = (const float*)d_in[8];
  const float* s1_whh0 = (const float*)d_in[9];
  const float* s1_b0   = (const float*)d_in[10];
  const float* s1_wih1 = (const float*)d_in[11];
  const float* s1_whh1 = (const float*)d_in[12];
  const float* s1_b1   = (const float*)d_in[13];
  const float* s2_wih0 = (const float*)d_in[14];
  const float* s2_whh0 = (const float*)d_in[15];
  const float* s2_b0   = (const float*)d_in[16];
  const float* s2_wih1 = (const float*)d_in[17];
  const float* s2_whh1 = (const float*)d_in[18];
  const float* s2_b1   = (const float*)d_in[19];
  const float* bn_g    = (const float*)d_in[20];
  const float* bn_b    = (const float*)d_in[21];
  const float* prebn_g = (const float*)d_in[22];
  const float* prebn_b = (const float*)d_in[23];
  const float* fc_w0   = (const float*)d_in[24];
  const float* fc_b0   = (const float*)d_in[25];
  const float* fc_w1   = (const float*)d_in[26];
  const float* fc_b1   = (const float*)d_in[27];
  const float* fc_w2   = (const float*)d_in[28];
  const float* fc_b2   = (const float*)d_in[29];
  const float* fcbn_g0 = (const float*)d_in[30];
  const float* fcbn_b0 = (const float*)d_in[31];
  const float* fcbn_g1 = (const float*)d_in[32];
  const float* fcbn_b1 = (const float*)d_in[33];
  const int* edge_index   = (const int*)d_in[34];
  const int* node_type    = (const int*)d_in[35];
  const int* batch        = (const int*)d_in[36];
  const int* assign_src   = (const int*)d_in[37];
  const int* assign_dst   = (const int*)d_in[38];
  const int* edge_index_2 = (const int*)d_in[39];
  const int* batch_2      = (const int*)d_in[40];
  (void)in_sizes; (void)n_in; (void)out_size; (void)ws_size;

  // dynamic-LDS opt-ins (host-side, graph-capture-safe). 96/64KB proven r6/r8.
  int fused_ok = (hipFuncSetAttribute((const void*)k_gru_fused,
                    hipFuncAttributeMaxDynamicSharedMemorySize, 98304) == hipSuccess);
  int tr4_ok = (hipFuncSetAttribute((const void*)k_tr4d,
                    hipFuncAttributeMaxDynamicSharedMemorySize, 65536) == hipSuccess);

  // ---- workspace layout ----
  float* Wp = (float*)d_ws;
  size_t o = 0;
  auto alloc = [&](size_t n){ float* p = Wp + o; o += n; return p; };
  float* h     = alloc((size_t)NN1*64);
  float* tr    = alloc((size_t)4*NN1*64);   // tr slabs; gi slabs in GRU fallback
  float* aggr  = alloc((size_t)NN1*64);
  float* coeff = alloc(NN1);
  float* h2    = alloc((size_t)NN2*64);
  float* cnt   = alloc(NN2);
  float* x1    = alloc(256*128);
  float* x2    = alloc(256*128);
  float* z     = alloc(256*256);
  float* z1    = alloc(256*128);
  float* z2    = alloc(256*64);
  float* stats = alloc(128);
  float* w4    = alloc(245760);
  float* wihT  = alloc(61440);
  float* wihW  = alloc(61440);
  float* whh4  = alloc(61440);
  float* s2sT1 = alloc(81920);
  float* s2sT2 = alloc(81920);
  int* etype = (int*)alloc(EE1);
  int* cnt1  = (int*)alloc(NN1);
  int* R1    = (int*)alloc(NN1 + 1);
  int* ep1   = (int*)alloc(EE1);
  int* cnt2  = (int*)alloc(NN2);
  int* R2    = (int*)alloc(NN2 + 1);
  int* ep2   = (int*)alloc(EE2);
  int* csum  = (int*)alloc(260);
  int* rb1   = (int*)alloc(257);
  int* rb2   = (int*)alloc(257);

  const int* src1 = edge_index;
  const int* dst1 = edge_index + EE1;
  const int* src2 = edge_index_2;
  const int* dst2 = edge_index_2 + EE2;

  k_etype<<<(EE1+255)/256, 256, 0, stream>>>(edge_attr, etype, EE1);
  k_copy<<<(NN1*64+255)/256, 256, 0, stream>>>(x_in, h, NN1*64);
  k_prep_msgw<<<(245760+255)/256, 256, 0, stream>>>(conv_w, w4);
  k_prep_gruw<<<(61440+255)/256, 256, 0, stream>>>(conv_wih, conv_whh, wihT, wihW, whh4);
  k_s2strans<<<(81920+255)/256, 256, 0, stream>>>(s1_wih0, s1_whh0, s1_wih1, s1_whh1, s2sT1);
  k_s2strans<<<(81920+255)/256, 256, 0, stream>>>(s2_wih0, s2_whh0, s2_wih1, s2_whh1, s2sT2);
  k_batchptr<<<(NN1+255)/256, 256, 0, stream>>>(batch, rb1, NN1, 256);
  k_batchptr<<<(NN2+255)/256, 256, 0, stream>>>(batch_2, rb2, NN2, 256);

  {  // level-1 CSR (keys = dst; ep stores packed row index t*NN1+src)
    int M = NN1, nchunk = (M + 1023)/1024;
    hipMemsetAsync(cnt1, 0, (size_t)M*sizeof(int), stream);
    k_hist<<<(EE1+255)/256, 256, 0, stream>>>(dst1, cnt1, EE1);
    k_chunksum<<<nchunk, 256, 0, stream>>>(cnt1, csum, M);
    k_chunkscan<<<1, 256, 0, stream>>>(csum, nchunk);
    k_chunkapply<<<nchunk, 256, 0, stream>>>(cnt1, csum, R1, cnt1, M);
    k_scatter<<<(EE1+255)/256, 256, 0, stream>>>(src1, dst1, etype, cnt1, ep1, EE1, NN1);
  }
  {  // level-2 CSR (single type: ep = src)
    int M = NN2, nchunk = (M + 1023)/1024;
    hipMemsetAsync(cnt2, 0, (size_t)M*sizeof(int), stream);
    k_hist<<<(EE2+255)/256, 256, 0, stream>>>(dst2, cnt2, EE2);
    k_chunksum<<<nchunk, 256, 0, stream>>>(cnt2, csum, M);
    k_chunkscan<<<1, 256, 0, stream>>>(csum, nchunk);
    k_chunkapply<<<nchunk, 256, 0, stream>>>(cnt2, csum, R2, cnt2, M);
    k_scatter<<<(EE2+255)/256, 256, 0, stream>>>(src2, dst2, nullptr, cnt2, ep2, EE2, NN2);
  }

  // GRU: fused (gi+gh+pointwise, 96KB LDS) or fallback (tr3 + finW)
  auto gru = [&](float* hbuf, int N, int lidx){
    if (fused_ok){
      k_gru_fused<<<256, 1024, 98304, stream>>>(aggr, hbuf,
          wihW + (size_t)lidx*12288, whh4 + (size_t)lidx*12288,
          conv_bih + lidx*192, conv_bhh + lidx*192, N);
    } else {
      k_tr3<<<768, 256, 0, stream>>>(aggr, wihT + (size_t)lidx*12288, tr, N);
      k_gru_finW<<<768, 256, 0, stream>>>(tr, hbuf, whh4 + (size_t)lidx*12288,
          conv_bih + lidx*192, conv_bhh + lidx*192, N);
    }
  };

  // ---- level-1: 3x MGGC(L=3) + BN + ReLU ----
  for (int i = 0; i < 3; ++i){
    k_coeff<<<(NN1+255)/256, 256, 0, stream>>>(conv_nt + i*9, node_type, coeff, NN1);
    for (int l = 0; l < 3; ++l){
      const float* W4l = w4 + (size_t)(i*3+l)*16384;   // 4 matrices, float4 layout
      if (tr4_ok){
        k_tr4d<<<512, 1024, 65536, stream>>>(h, W4l, coeff, tr, NN1);
      } else {
        for (int t = 0; t < 4; ++t)
          k_tr1<<<1024, 256, 0, stream>>>(h, W4l + (size_t)t*4096, coeff,
                                          tr + (size_t)t*NN1*64, NN1);
      }
      k_sweep_p<<<(NN1+3)/4, 256, 0, stream>>>(tr, R1, ep1, aggr, NN1);
      gru(h, NN1, i);
    }
    hipMemsetAsync(stats, 0, 128*sizeof(float), stream);
    k_bnstats<<<256, 256, 0, stream>>>(h, stats, NN1);
    k_bnapply<<<(NN1*64+255)/256, 256, 0, stream>>>(h, stats, bn_g + i*64, bn_b + i*64, NN1, 1);
  }

  // ---- set2set (single fused kernel, 1024 threads/graph) ----
  k_set2set<<<256, 1024, 0, stream>>>(h, rb1, s2sT1, s1_b0, s1_b1, x1);

  // ---- avg_pool ----
  hipMemsetAsync(h2, 0, (size_t)NN2*64*sizeof(float), stream);
  hipMemsetAsync(cnt, 0, (size_t)NN2*sizeof(float), stream);
  k_pool_acc<<<(AA*64+255)/256, 256, 0, stream>>>(h, assign_src, assign_dst, h2, cnt, AA);
  k_pool_div<<<(NN2*64+255)/256, 256, 0, stream>>>(h2, cnt, NN2);

  // ---- level-2: 2x relu(MGGC(L=3)), only edge type 0 ----
  for (int L = 3; L < 5; ++L){
    for (int l = 0; l < 3; ++l){
      const float* W4l = w4 + (size_t)(L*3+l)*16384;   // t=0 slice used
      k_tr1<<<1250, 256, 0, stream>>>(h2, W4l, nullptr, tr, NN2);
      k_sweep_p<<<(NN2+3)/4, 256, 0, stream>>>(tr, R2, ep2, aggr, NN2);
      gru(h2, NN2, L);
    }
    k_relu<<<(NN2*64+255)/256, 256, 0, stream>>>(h2, NN2*64);
  }

  k_set2set<<<256, 1024, 0, stream>>>(h2, rb2, s2sT2, s2_b0, s2_b1, x2);

  // ---- head ----
  k_concat<<<256, 256, 0, stream>>>(x1, x2, z);
  k_bn_par<<<256, 256, 0, stream>>>(z, prebn_g, prebn_b, 256, 0);
  k_fc<<<256, 128, 0, stream>>>(z, fc_w0, fc_b0, z1, 256, 128);
  k_bn_par<<<128, 256, 0, stream>>>(z1, fcbn_g0, fcbn_b0, 128, 1);
  k_fc<<<256, 64, 0, stream>>>(z1, fc_w1, fc_b1, z2, 128, 64);
  k_bn_par<<<64, 256, 0, stream>>>(z2, fcbn_g1, fcbn_b1, 64, 1);
  k_fc_out<<<4, 64, 0, stream>>>(z2, fc_w2, fc_b2, (float*)d_out);
}

// Round 11
// 2034.708 us; speedup vs baseline: 1.3916x; 1.0775x over previous
//
#include <hip/hip_runtime.h>

#define NN1 60000
#define EE1 600000
#define NN2 20000
#define EE2 150000
#define AA  60000

__device__ __forceinline__ float sigf(float x){ return 1.f/(1.f+expf(-x)); }
// wave-uniform broadcast of lane sl's value. sl may be a RUNTIME uniform
// (v_readlane_b32 takes an SGPR lane index), so loops need not unroll.
__device__ __forceinline__ float rlane(float v, int sl){
  return __int_as_float(__builtin_amdgcn_readlane(__float_as_int(v), sl));
}
// Broadcast 4 channels (ld.x..ld.w) of lane SL, then FMA into named scalars.
// ALL state is named scalars -> guaranteed VGPRs (rounds 1/3: arrays spill).
#define RL4(SL) hx = rlane(ld.x, SL); hy = rlane(ld.y, SL); hz = rlane(ld.z, SL); hw = rlane(ld.w, SL);
#define FMA4(A, W) A = fmaf(hx, W.x, A); A = fmaf(hy, W.y, A); A = fmaf(hz, W.z, A); A = fmaf(hw, W.w, A);

// ---------- elementwise ----------
__global__ void k_relu(float* a, int n){
  int i = blockIdx.x*blockDim.x + threadIdx.x;
  if (i < n) a[i] = fmaxf(a[i], 0.f);
}
__global__ void k_copy(const float* __restrict__ a, float* __restrict__ o, int n){
  int i = blockIdx.x*blockDim.x + threadIdx.x;
  if (i < n) o[i] = a[i];
}

// ---------- edge type ----------
__global__ void k_etype(const float* __restrict__ ea, int* __restrict__ etype, int E){
  int e = blockIdx.x*blockDim.x + threadIdx.x;
  if (e >= E) return;
  const float* p = ea + (size_t)e*10;
  float best = p[0]; int bi = 0;
  #pragma unroll
  for (int k = 1; k < 4; ++k){ float v = p[k]; if (v > best){ best = v; bi = k; } }
  etype[e] = bi;
}

__global__ void k_coeff(const float* __restrict__ nt, const int* __restrict__ node_type,
                        float* __restrict__ coeff, int N){
  int n = blockIdx.x*blockDim.x + threadIdx.x;
  if (n < N) coeff[n] = nt[node_type[n]];
}

// ---------- batch row pointers (batch sorted ascending) ----------
__global__ void k_batchptr(const int* __restrict__ batch, int* __restrict__ rb, int N, int B){
  int n = blockIdx.x*blockDim.x + threadIdx.x;
  if (n >= N) return;
  int b = batch[n];
  if (n == 0){ for (int g = 0; g <= b; ++g) rb[g] = 0; }
  else {
    int pb = batch[n-1];
    for (int g = pb+1; g <= b; ++g) rb[g] = n;
  }
  if (n == N-1){ for (int g = b+1; g <= B; ++g) rb[g] = N; }
}

// ---------- weight prep ----------
// msg weights: conv_w[m][c][d] (m = (li*3+l)*4+t) -> w4[m][c4][d][q],
// float4 element (c4,d) = { W[4c4+0][d], W[4c4+1][d], W[4c4+2][d], W[4c4+3][d] }.
// In-kernel lane d reads float4 index c4*64+d: contiguous -> conflict-free b128.
__global__ void k_prep_msgw(const float* __restrict__ w, float* __restrict__ w4){
  int idx = blockIdx.x*256 + threadIdx.x;   // 60*4096 = 245760
  if (idx >= 245760) return;
  int m = idx >> 12, r = idx & 4095;
  int c4 = r >> 8, d = (r >> 2) & 63, q = r & 3;
  w4[idx] = w[m*4096 + (4*c4+q)*64 + d];
}
// GRU weights, three layouts:
//  wihT[l][t][c4][d][q] = wih[l][(64t+d)][4c4+q]  (tr3 fallback: lane d owns row 64t+d)
//  wihW[l][c4][j][q]    = wih[l][j][4c4+q]        (fused: lane l owns rows {l,64+l,128+l})
//  whh4[l][c4][j][q]    = whh[l][j][4c4+q]
__global__ void k_prep_gruw(const float* __restrict__ wih, const float* __restrict__ whh,
                            float* __restrict__ wihT, float* __restrict__ wihW,
                            float* __restrict__ whh4){
  int idx = blockIdx.x*256 + threadIdx.x;   // 5*12288 = 61440 each
  if (idx >= 61440) return;
  {
    int l = idx / 12288, r = idx % 12288;
    int t = r >> 12, rr = r & 4095;
    int c4 = rr >> 8, d = (rr >> 2) & 63, q = rr & 3;
    wihT[idx] = wih[l*12288 + (64*t + d)*64 + 4*c4 + q];
  }
  {
    int l = idx / 12288, rr = idx % 12288;
    int e = rr >> 2, q = rr & 3;
    int c4 = e / 192, j = e - c4*192;
    wihW[idx] = wih[l*12288 + j*64 + 4*c4 + q];
    whh4[idx] = whh[l*12288 + j*64 + 4*c4 + q];
  }
}

// ---------- set2set LSTM weight transpose to [k][j] (coalesced over gate row j) ----------
__global__ void k_s2strans(const float* __restrict__ wih0, const float* __restrict__ whh0,
                           const float* __restrict__ wih1, const float* __restrict__ whh1,
                           float* __restrict__ T){
  int idx = blockIdx.x*256 + threadIdx.x;
  if (idx < 32768){ int k = idx >> 8, j = idx & 255; T[idx] = wih0[j*128 + k]; }
  else if (idx < 49152){ int r = idx - 32768; int k = r >> 8, j = r & 255; T[idx] = whh0[j*64 + k]; }
  else if (idx < 65536){ int r = idx - 49152; int k = r >> 8, j = r & 255; T[idx] = wih1[j*64 + k]; }
  else if (idx < 81920){ int r = idx - 65536; int k = r >> 8, j = r & 255; T[idx] = whh1[j*64 + k]; }
}

// ---------- CSR build ----------
__global__ void k_hist(const int* __restrict__ dst, int* __restrict__ cnt, int E){
  int e = blockIdx.x*blockDim.x + threadIdx.x;
  if (e >= E) return;
  atomicAdd(&cnt[dst[e]], 1);
}
__global__ void k_chunksum(const int* __restrict__ cnt, int* __restrict__ csum, int M){
  __shared__ int sh[256];
  int base = blockIdx.x*1024;
  int s = 0;
  for (int i = threadIdx.x; i < 1024; i += 256){
    int idx = base + i;
    if (idx < M) s += cnt[idx];
  }
  sh[threadIdx.x] = s;
  __syncthreads();
  for (int o = 128; o; o >>= 1){
    if (threadIdx.x < o) sh[threadIdx.x] += sh[threadIdx.x + o];
    __syncthreads();
  }
  if (threadIdx.x == 0) csum[blockIdx.x] = sh[0];
}
__global__ void k_chunkscan(int* __restrict__ csum, int nchunk){
  __shared__ int sh[256];
  int i = threadIdx.x;
  int v = (i < nchunk) ? csum[i] : 0;
  sh[i] = v; __syncthreads();
  for (int o = 1; o < 256; o <<= 1){
    int y = (i >= o) ? sh[i-o] : 0;
    __syncthreads();
    sh[i] += y;
    __syncthreads();
  }
  if (i < nchunk) csum[i] = sh[i] - v;
  if (i == 255) csum[nchunk] = sh[255];
}
__global__ void k_chunkapply(const int* __restrict__ cnt, const int* __restrict__ csum,
                             int* __restrict__ R, int* __restrict__ cur, int M){
  __shared__ int sh[256];
  int base = blockIdx.x*1024;
  int i0 = base + threadIdx.x*4;
  int v[4]; int s = 0;
  #pragma unroll
  for (int k = 0; k < 4; ++k){ int idx = i0 + k; v[k] = (idx < M) ? cnt[idx] : 0; s += v[k]; }
  sh[threadIdx.x] = s; __syncthreads();
  for (int o = 1; o < 256; o <<= 1){
    int y = (threadIdx.x >= o) ? sh[threadIdx.x-o] : 0;
    __syncthreads();
    sh[threadIdx.x] += y;
    __syncthreads();
  }
  int run = csum[blockIdx.x] + sh[threadIdx.x] - s;
  #pragma unroll
  for (int k = 0; k < 4; ++k){
    int idx = i0 + k;
    if (idx < M){ R[idx] = run; cur[idx] = run; run += v[k]; }
  }
  if (threadIdx.x == 255 && base + 1024 >= M) R[M] = csum[blockIdx.x] + sh[255];
}
// scatter packs the FULL tr row index (t*N + src, < 2^31) so the sweep's
// per-edge address math is a single shift.
__global__ void k_scatter(const int* __restrict__ src, const int* __restrict__ dst,
                          const int* __restrict__ etype, int* __restrict__ cur,
                          int* __restrict__ ep, int E, int N){
  int e = blockIdx.x*blockDim.x + threadIdx.x;
  if (e >= E) return;
  int t = etype ? etype[e] : 0;
  int pos = atomicAdd(&cur[dst[e]], 1);
  ep[pos] = t*N + src[e];
}

// ---------- dense transforms: LDS weights + 1 coalesced load + readlane ----------
// tr[t][n][d] = coeff[n] * sum_c h[n][c]*W[t][c][d].
// Per 4-node group: ONE dwordx4/wave; readlane broadcasts; NAMED-SCALAR
// accumulators (arrays spill: r1/r3). Weights in LDS, conflict-free b128.

// 4 matrices in one pass: 64 KB LDS, 1024 thr, rl:fma = 1:4.  [r8: -440us]
__global__ __launch_bounds__(1024, 4) void k_tr4d(
    const float* __restrict__ h, const float* __restrict__ W4,
    const float* __restrict__ coeff, float* __restrict__ tr, int N){
  extern __shared__ float4 wl[];           // [4][1024] = 64 KB
  for (int i = threadIdx.x; i < 4096; i += 1024) wl[i] = ((const float4*)W4)[i];
  __syncthreads();
  int lane = threadIdx.x & 63, wv = threadIdx.x >> 6;   // 16 waves
  int ng = N >> 2, stride = gridDim.x*16;
  for (int g = blockIdx.x*16 + wv; g < ng; g += stride){
    int n0 = g << 2;
    float4 ld = ((const float4*)(h + ((size_t)n0 << 6)))[lane];
    float a00=0.f,a01=0.f,a02=0.f,a03=0.f;
    float a10=0.f,a11=0.f,a12=0.f,a13=0.f;
    float a20=0.f,a21=0.f,a22=0.f,a23=0.f;
    float a30=0.f,a31=0.f,a32=0.f,a33=0.f;
    for (int c4 = 0; c4 < 16; ++c4){
      int wb = (c4 << 6) + lane;
      float4 w0 = wl[wb], w1 = wl[1024+wb], w2 = wl[2048+wb], w3 = wl[3072+wb];
      float hx, hy, hz, hw;
      RL4(c4)     FMA4(a00,w0) FMA4(a10,w1) FMA4(a20,w2) FMA4(a30,w3)
      RL4(16|c4)  FMA4(a01,w0) FMA4(a11,w1) FMA4(a21,w2) FMA4(a31,w3)
      RL4(32|c4)  FMA4(a02,w0) FMA4(a12,w1) FMA4(a22,w2) FMA4(a32,w3)
      RL4(48|c4)  FMA4(a03,w0) FMA4(a13,w1) FMA4(a23,w2) FMA4(a33,w3)
    }
    float4 cv = ((const float4*)coeff)[g];
    a00*=cv.x; a01*=cv.y; a02*=cv.z; a03*=cv.w;
    a10*=cv.x; a11*=cv.y; a12*=cv.z; a13*=cv.w;
    a20*=cv.x; a21*=cv.y; a22*=cv.z; a23*=cv.w;
    a30*=cv.x; a31*=cv.y; a32*=cv.z; a33*=cv.w;
    float* o0 = tr + ((size_t)n0 << 6) + lane;
    o0[0]=a00; o0[64]=a01; o0[128]=a02; o0[192]=a03;
    float* o1 = tr + (((size_t)N + n0) << 6) + lane;
    o1[0]=a10; o1[64]=a11; o1[128]=a12; o1[192]=a13;
    float* o2 = tr + (((size_t)2*N + n0) << 6) + lane;
    o2[0]=a20; o2[64]=a21; o2[128]=a22; o2[192]=a23;
    float* o3 = tr + (((size_t)3*N + n0) << 6) + lane;
    o3[0]=a30; o3[64]=a31; o3[128]=a32; o3[192]=a33;
  }
}

// single-matrix variant (level-2; also tr4d fallback), 16 KB static LDS
__global__ __launch_bounds__(256) void k_tr1(
    const float* __restrict__ h, const float* __restrict__ W4,
    const float* __restrict__ coeff, float* __restrict__ tr, int N){
  __shared__ float4 wl[1024];                 // 16 KB
  for (int i = threadIdx.x; i < 1024; i += 256) wl[i] = ((const float4*)W4)[i];
  __syncthreads();
  int lane = threadIdx.x & 63, w = threadIdx.x >> 6;
  int ng = N >> 2, stride = gridDim.x*4;
  for (int g = blockIdx.x*4 + w; g < ng; g += stride){
    int n0 = g << 2;
    float4 ld = ((const float4*)(h + ((size_t)n0 << 6)))[lane];
    float a0=0.f, a1=0.f, a2=0.f, a3=0.f;
    for (int c4 = 0; c4 < 16; ++c4){
      float4 w0 = wl[(c4 << 6) + lane];
      float hx, hy, hz, hw;
      RL4(c4)       FMA4(a0, w0)
      RL4(16|c4)    FMA4(a1, w0)
      RL4(32|c4)    FMA4(a2, w0)
      RL4(48|c4)    FMA4(a3, w0)
    }
    if (coeff){
      float4 cv = ((const float4*)coeff)[g];
      a0 *= cv.x; a1 *= cv.y; a2 *= cv.z; a3 *= cv.w;
    }
    float* o0 = tr + ((size_t)n0 << 6) + lane;
    o0[0] = a0; o0[64] = a1; o0[128] = a2; o0[192] = a3;
  }
}

// ---------- merged sweep (gather tr rows per dst via CSR) ----------
// ep holds the packed row index (t*N+src) -> addr = (ridx<<6)+lane.
// 4-unroll with 4 independent accumulators: 4 gathers in flight per wave.
__global__ void k_sweep_p(const float* __restrict__ tr, const int* __restrict__ R,
                          const int* __restrict__ ep, float* __restrict__ aggr, int N){
  int w = threadIdx.x >> 6, lane = threadIdx.x & 63;
  int d = blockIdx.x*4 + w;
  if (d >= N) return;
  int p = R[d], pend = R[d+1];
  float a0=0.f, a1=0.f, a2=0.f, a3=0.f;
  while (p < pend){
    int m = pend - p; if (m > 64) m = 64;
    int ev = (lane < m) ? ep[p + lane] : 0;
    int j = 0;
    for (; j + 4 <= m; j += 4){
      int r0 = __shfl(ev, j),   r1 = __shfl(ev, j+1);
      int r2 = __shfl(ev, j+2), r3 = __shfl(ev, j+3);
      float v0 = tr[((size_t)r0 << 6) + lane];
      float v1 = tr[((size_t)r1 << 6) + lane];
      float v2 = tr[((size_t)r2 << 6) + lane];
      float v3 = tr[((size_t)r3 << 6) + lane];
      a0 += v0; a1 += v1; a2 += v2; a3 += v3;
    }
    for (; j < m; ++j){
      int r0 = __shfl(ev, j);
      a0 += tr[((size_t)r0 << 6) + lane];
    }
    p += m;
  }
  aggr[(size_t)d*64 + lane] = (a0 + a1) + (a2 + a3);
}

// ---------- tr3: GRU-fallback gi transform (LDS weights + readlane) ----------
__global__ __launch_bounds__(256) void k_tr3(
    const float* __restrict__ h, const float* __restrict__ W4,
    float* __restrict__ tr, int N){
  __shared__ float4 wl[3072];                 // 48 KB (3 matrices)
  for (int i = threadIdx.x; i < 3072; i += 256) wl[i] = ((const float4*)W4)[i];
  __syncthreads();
  int lane = threadIdx.x & 63, w = threadIdx.x >> 6;
  int ng = N >> 2, stride = gridDim.x*4;
  for (int g = blockIdx.x*4 + w; g < ng; g += stride){
    int n0 = g << 2;
    float4 ld = ((const float4*)(h + ((size_t)n0 << 6)))[lane];
    float a00=0.f,a01=0.f,a02=0.f,a03=0.f;
    float a10=0.f,a11=0.f,a12=0.f,a13=0.f;
    float a20=0.f,a21=0.f,a22=0.f,a23=0.f;
    for (int c4 = 0; c4 < 16; ++c4){
      float4 w0 = wl[(c4 << 6) + lane];
      float4 w1 = wl[1024 + (c4 << 6) + lane];
      float4 w2 = wl[2048 + (c4 << 6) + lane];
      float hx, hy, hz, hw;
      RL4(c4)       FMA4(a00, w0) FMA4(a10, w1) FMA4(a20, w2)
      RL4(16|c4)    FMA4(a01, w0) FMA4(a11, w1) FMA4(a21, w2)
      RL4(32|c4)    FMA4(a02, w0) FMA4(a12, w1) FMA4(a22, w2)
      RL4(48|c4)    FMA4(a03, w0) FMA4(a13, w1) FMA4(a23, w2)
    }
    float* o0 = tr + ((size_t)n0 << 6) + lane;
    o0[0] = a00; o0[64] = a01; o0[128] = a02; o0[192] = a03;
    float* o1 = tr + (((size_t)N + n0) << 6) + lane;
    o1[0] = a10; o1[64] = a11; o1[128] = a12; o1[192] = a13;
    float* o2 = tr + (((size_t)2*N + n0) << 6) + lane;
    o2[0] = a20; o2[64] = a21; o2[128] = a22; o2[192] = a23;
  }
}

// ---------- fully fused GRU: both GEMVs + pointwise in ONE kernel ----------
// r11: broadcasts moved off the VALU pipe. r10 counters: 79.5us, VALUBusy 70%
// -> issue-bound; 512 of ~2160 VALU issues/group were v_readlane. Each wave
// now stages its 4-node tile (la,ld = 2KB) in WAVE-PRIVATE LDS scratch
// (no barrier: same-wave write->read, lgkmcnt auto), and the broadcasts
// become 128 wave-uniform ds_read_b128 on the separate LDS pipe:
// stg[(k<<4)+c4] = {la[n0+k][4c4..+3]}. VALU issues 2160 -> ~1660.
// LDS 96KB weights + 32KB staging = 128KB (still 1 block/CU, 16 waves).
#define GACC2(K, R, Z, P, Q) { \
  float4 av = stg[((K) << 4) + c4]; \
  float4 hv = stg[64 + ((K) << 4) + c4]; \
  R = fmaf(av.x,iwr.x,R); R = fmaf(av.y,iwr.y,R); R = fmaf(av.z,iwr.z,R); R = fmaf(av.w,iwr.w,R); \
  R = fmaf(hv.x,hwr.x,R); R = fmaf(hv.y,hwr.y,R); R = fmaf(hv.z,hwr.z,R); R = fmaf(hv.w,hwr.w,R); \
  Z = fmaf(av.x,iwz.x,Z); Z = fmaf(av.y,iwz.y,Z); Z = fmaf(av.z,iwz.z,Z); Z = fmaf(av.w,iwz.w,Z); \
  Z = fmaf(hv.x,hwz.x,Z); Z = fmaf(hv.y,hwz.y,Z); Z = fmaf(hv.z,hwz.z,Z); Z = fmaf(hv.w,hwz.w,Z); \
  P = fmaf(av.x,iwn.x,P); P = fmaf(av.y,iwn.y,P); P = fmaf(av.z,iwn.z,P); P = fmaf(av.w,iwn.w,P); \
  Q = fmaf(hv.x,hwn.x,Q); Q = fmaf(hv.y,hwn.y,Q); Q = fmaf(hv.z,hwn.z,Q); Q = fmaf(hv.w,hwn.w,Q); }
#define GFIN(K, R, Z, P, Q) { \
    size_t off = base + ((size_t)(K) << 6) + lane; \
    float hv = h[off]; \
    float r = sigf(R), z = sigf(Z); \
    float nn = tanhf(P + r*Q); \
    h[off] = (1.f - z)*nn + z*hv; }
__global__ __launch_bounds__(1024, 4) void k_gru_fused(
    const float* __restrict__ aggr, float* __restrict__ h,
    const float* __restrict__ wihW, const float* __restrict__ whhW,
    const float* __restrict__ bih, const float* __restrict__ bhh, int N){
  extern __shared__ float4 wl[];           // [6144 w] + [16][128] staging = 128 KB
  for (int i = threadIdx.x; i < 6144; i += 1024)
    wl[i] = (i < 3072) ? ((const float4*)wihW)[i] : ((const float4*)whhW)[i - 3072];
  __syncthreads();
  const float4* wi = wl;
  const float4* wh = wl + 3072;
  int lane = threadIdx.x & 63, wv = threadIdx.x >> 6;
  float4* stg = wl + 6144 + wv*128;        // wave-private: [0..63]=la, [64..127]=ld
  float br  = bih[lane]     + bhh[lane];
  float bz  = bih[64+lane]  + bhh[64+lane];
  float bp  = bih[128+lane];                // gi_n bias
  float bq  = bhh[128+lane];                // gh_n bias
  int ng = N >> 2, stride = gridDim.x*16;
  for (int g = blockIdx.x*16 + wv; g < ng; g += stride){
    int n0 = g << 2;
    size_t base = (size_t)n0 << 6;
    float4 la = ((const float4*)(aggr + base))[lane];
    float4 ld = ((const float4*)(h + base))[lane];
    stg[lane] = la;
    stg[64 + lane] = ld;
    float r0=br, r1=br, r2=br, r3=br;
    float z0=bz, z1=bz, z2=bz, z3=bz;
    float p0=bp, p1=bp, p2=bp, p3=bp;
    float q0=bq, q1=bq, q2=bq, q3=bq;
    for (int c4 = 0; c4 < 16; ++c4){
      int wb = c4*192 + lane;
      float4 iwr = wi[wb], iwz = wi[wb+64], iwn = wi[wb+128];
      float4 hwr = wh[wb], hwz = wh[wb+64], hwn = wh[wb+128];
      GACC2(0, r0, z0, p0, q0)
      GACC2(1, r1, z1, p1, q1)
      GACC2(2, r2, z2, p2, q2)
      GACC2(3, r3, z3, p3, q3)
    }
    GFIN(0, r0, z0, p0, q0)
    GFIN(1, r1, z1, p1, q1)
    GFIN(2, r2, z2, p2, q2)
    GFIN(3, r3, z3, p3, q3)
  }
}

// ---------- GRU finalize fallback (used only if 128KB dynamic LDS refused) ----------
#define GRUACC(SL, RK, ZK, NK) RL4(SL) FMA4(RK, wr) FMA4(ZK, wz) FMA4(NK, wn)
#define GRUFIN(K, RK, ZK, NK) { \
    size_t off = base + (K << 6) + lane; \
    float gir = gi[off], giz = gi[S + off], gin = gi[2*S + off]; \
    float hv = h[off]; \
    float r = sigf(gir + bir + RK); \
    float z = sigf(giz + biz + ZK); \
    float nv = tanhf(gin + bin_ + r*NK); \
    h[off] = (1.f - z)*nv + z*hv; }
__global__ __launch_bounds__(256, 3) void k_gru_finW(
    const float* __restrict__ gi, float* __restrict__ h,
    const float* __restrict__ whh4,
    const float* __restrict__ bih, const float* __restrict__ bhh, int N){
  __shared__ float4 wh[3072];              // [c4][192] = whh[j][4c4+q], 48KB
  for (int i = threadIdx.x; i < 3072; i += 256) wh[i] = ((const float4*)whh4)[i];
  __syncthreads();
  int lane = threadIdx.x & 63, w = threadIdx.x >> 6;
  float bir = bih[lane], biz = bih[64+lane], bin_ = bih[128+lane];
  float bhr = bhh[lane], bhz = bhh[64+lane], bhn = bhh[128+lane];
  size_t S = (size_t)N << 6;
  int ng = N >> 2, stride = gridDim.x*4;
  for (int g = blockIdx.x*4 + w; g < ng; g += stride){
    int n0 = g << 2;
    size_t base = (size_t)n0 << 6;
    float4 ld = ((const float4*)(h + base))[lane];
    float ar0=bhr, ar1=bhr, ar2=bhr, ar3=bhr;
    float az0=bhz, az1=bhz, az2=bhz, az3=bhz;
    float an0=bhn, an1=bhn, an2=bhn, an3=bhn;
    for (int c4 = 0; c4 < 16; ++c4){
      int wb = c4*192 + lane;
      float4 wr = wh[wb];
      float4 wz = wh[wb + 64];
      float4 wn = wh[wb + 128];
      float hx, hy, hz, hw;
      GRUACC(c4,    ar0, az0, an0)
      GRUACC(16|c4, ar1, az1, an1)
      GRUACC(32|c4, ar2, az2, an2)
      GRUACC(48|c4, ar3, az3, an3)
    }
    GRUFIN(0, ar0, az0, an0)
    GRUFIN(1, ar1, az1, an1)
    GRUFIN(2, ar2, az2, an2)
    GRUFIN(3, ar3, az3, an3)
  }
}

// ---------- batch norm over nodes ----------
__global__ void k_bnstats(const float* __restrict__ h, float* __restrict__ stats, int N){
  int c = threadIdx.x & 63;
  int g = threadIdx.x >> 6;
  float s = 0.f, s2 = 0.f;
  for (int n = blockIdx.x*4 + g; n < N; n += gridDim.x*4){
    float v = h[(size_t)n*64 + c]; s += v; s2 += v*v;
  }
  __shared__ float sh[4][64], sh2[4][64];
  sh[g][c] = s; sh2[g][c] = s2;
  __syncthreads();
  if (g == 0){
    float ts = sh[0][c]+sh[1][c]+sh[2][c]+sh[3][c];
    float t2 = sh2[0][c]+sh2[1][c]+sh2[2][c]+sh2[3][c];
    atomicAdd(&stats[c], ts); atomicAdd(&stats[64+c], t2);
  }
}
__global__ void k_bnapply(float* __restrict__ h, const float* __restrict__ stats,
                          const float* __restrict__ g, const float* __restrict__ b,
                          int N, int relu){
  int i = blockIdx.x*blockDim.x + threadIdx.x;
  if (i >= N*64) return;
  int c = i & 63;
  float inv = 1.f/(float)N;
  float mean = stats[c]*inv;
  float var  = stats[64+c]*inv - mean*mean;
  float y = (h[i]-mean)*rsqrtf(var + 1e-5f)*g[c] + b[c];
  if (relu) y = fmaxf(y, 0.f);
  h[i] = y;
}

// ---------- avg_pool ----------
__global__ void k_pool_acc(const float* __restrict__ h, const int* __restrict__ asrc,
                           const int* __restrict__ adst, float* __restrict__ h2,
                           float* __restrict__ cnt, int A){
  int i = blockIdx.x*blockDim.x + threadIdx.x;
  if (i >= A*64) return;
  int a = i >> 6, c = i & 63;
  int s = asrc[a], d = adst[a];
  atomicAdd(&h2[(size_t)d*64 + c], h[(size_t)s*64 + c]);
  if (c == 0) atomicAdd(&cnt[d], 1.f);
}
__global__ void k_pool_div(float* __restrict__ h2, const float* __restrict__ cnt, int N){
  int i = blockIdx.x*blockDim.x + threadIdx.x;
  if (i >= N*64) return;
  h2[i] = h2[i] / fmaxf(cnt[i >> 6], 1.f);
}

// ---------- fully fused set2set: one block (1024 thr = 16 waves) per graph ----------
// ONLINE softmax attention — single pass over x per step. Wave partials
// (wmax,wsum,racc) combined exactly via exp(wmax-M) scaling.  [r10: -100us]
__global__ __launch_bounds__(1024) void k_set2set(const float* __restrict__ x, const int* __restrict__ rb,
                          const float* __restrict__ T,
                          const float* __restrict__ b0, const float* __restrict__ b1,
                          float* __restrict__ xout){
  int b = blockIdx.x, j = threadIdx.x;
  int w = j >> 6, lane = j & 63;
  __shared__ float qstar[128], h0[64], c0[64], h1[64], c1[64];
  __shared__ float gs[256], wmax[16], wsum[16], racc[16][64];
  if (j < 128) qstar[j] = 0.f;
  if (j < 64){ h0[j] = 0.f; c0[j] = 0.f; h1[j] = 0.f; c1[j] = 0.f; }
  __syncthreads();
  int n0 = rb[b], n1 = rb[b+1];
  const float* T0 = T;            // wih0T [128][256]
  const float* T1 = T + 32768;    // whh0T [64][256]
  const float* T2 = T + 49152;    // wih1T [64][256]
  const float* T3 = T + 65536;    // whh1T [64][256]
  for (int s = 0; s < 5; ++s){
    if (j < 256){
      float a0 = b0[j], a1 = 0.f, a2 = 0.f, a3 = 0.f;
      #pragma unroll 4
      for (int k = 0; k < 128; k += 4){
        a0 = fmaf(T0[(k+0)*256 + j], qstar[k+0], a0);
        a1 = fmaf(T0[(k+1)*256 + j], qstar[k+1], a1);
        a2 = fmaf(T0[(k+2)*256 + j], qstar[k+2], a2);
        a3 = fmaf(T0[(k+3)*256 + j], qstar[k+3], a3);
      }
      #pragma unroll 4
      for (int k = 0; k < 64; k += 4){
        a0 = fmaf(T1[(k+0)*256 + j], h0[k+0], a0);
        a1 = fmaf(T1[(k+1)*256 + j], h0[k+1], a1);
        a2 = fmaf(T1[(k+2)*256 + j], h0[k+2], a2);
        a3 = fmaf(T1[(k+3)*256 + j], h0[k+3], a3);
      }
      gs[j] = (a0 + a1) + (a2 + a3);
    }
    __syncthreads();
    if (j < 64){
      float ig = sigf(gs[j]);
      float fg = sigf(gs[64+j]);
      float gg = tanhf(gs[128+j]);
      float og = sigf(gs[192+j]);
      float cn = fg*c0[j] + ig*gg;
      c0[j] = cn;
      h0[j] = og*tanhf(cn);
    }
    __syncthreads();
    if (j < 256){
      float a0 = b1[j], a1 = 0.f, a2 = 0.f, a3 = 0.f;
      #pragma unroll 4
      for (int k = 0; k < 64; k += 4){
        a0 = fmaf(T2[(k+0)*256 + j], h0[k+0], a0);
        a1 = fmaf(T2[(k+1)*256 + j], h0[k+1], a1);
        a2 = fmaf(T2[(k+2)*256 + j], h0[k+2], a2);
        a3 = fmaf(T2[(k+3)*256 + j], h0[k+3], a3);
      }
      #pragma unroll 4
      for (int k = 0; k < 64; k += 4){
        a0 = fmaf(T3[(k+0)*256 + j], h1[k+0], a0);
        a1 = fmaf(T3[(k+1)*256 + j], h1[k+1], a1);
        a2 = fmaf(T3[(k+2)*256 + j], h1[k+2], a2);
        a3 = fmaf(T3[(k+3)*256 + j], h1[k+3], a3);
      }
      gs[j] = (a0 + a1) + (a2 + a3);
    }
    __syncthreads();
    if (j < 64){
      float ig = sigf(gs[j]);
      float fg = sigf(gs[64+j]);
      float gg = tanhf(gs[128+j]);
      float og = sigf(gs[192+j]);
      float cn = fg*c1[j] + ig*gg;
      c1[j] = cn;
      float hn = og*tanhf(cn);
      h1[j] = hn;
      qstar[j] = hn;
    }
    __syncthreads();
    // ---- online-softmax attention: ONE pass over the graph's nodes ----
    float lmax = -3.4e38f, lsum = 0.f, lr = 0.f;
    for (int n = n0 + w; n < n1; n += 16){
      float xv = x[(size_t)n*64 + lane];
      float v = xv*qstar[lane];
      #pragma unroll
      for (int o = 32; o; o >>= 1) v += __shfl_xor(v, o);
      float nm = fmaxf(lmax, v);
      float corr = expf(lmax - nm);    // 0 on first node (lmax=-inf-ish)
      float e = expf(v - nm);
      lsum = fmaf(lsum, corr, e);
      lr   = fmaf(lr, corr, e*xv);
      lmax = nm;
    }
    if (lane == 0){ wmax[w] = lmax; wsum[w] = lsum; }
    racc[w][lane] = lr;
    __syncthreads();
    if (j < 64){
      float M = wmax[0];
      #pragma unroll
      for (int k = 1; k < 16; ++k) M = fmaxf(M, wmax[k]);
      float denom = 0.f, r = 0.f;
      #pragma unroll
      for (int k = 0; k < 16; ++k){
        float sc = expf(wmax[k] - M);  // 0 for empty waves
        denom = fmaf(wsum[k], sc, denom);
        r     = fmaf(racc[k][j], sc, r);
      }
      qstar[64 + j] = (denom > 0.f) ? (r/denom) : 0.f;
    }
    __syncthreads();
  }
  if (j < 128) xout[(size_t)b*128 + j] = qstar[j];
}

// ---------- head ----------
__global__ void k_concat(const float* __restrict__ x1, const float* __restrict__ x2,
                         float* __restrict__ z){
  int i = blockIdx.x*blockDim.x + threadIdx.x;
  if (i >= 256*256) return;
  int b = i >> 8, c = i & 255;
  z[i] = (c < 128) ? x1[b*128 + c] : x2[b*128 + (c - 128)];
}
__global__ void k_bn_par(float* __restrict__ X, const float* __restrict__ g,
                         const float* __restrict__ b, int F, int relu){
  int f = blockIdx.x, i = threadIdx.x;
  float v = X[(size_t)i*F + f];
  __shared__ float s1[256], s2[256];
  s1[i] = v; s2[i] = v*v;
  __syncthreads();
  for (int o = 128; o; o >>= 1){
    if (i < o){ s1[i] += s1[i+o]; s2[i] += s2[i+o]; }
    __syncthreads();
  }
  float mean = s1[0]*(1.f/256.f);
  float var  = s2[0]*(1.f/256.f) - mean*mean;
  float y = (v - mean)*rsqrtf(var + 1e-5f)*g[f] + b[f];
  if (relu) y = fmaxf(y, 0.f);
  X[(size_t)i*F + f] = y;
}
__global__ void k_fc(const float* __restrict__ X, const float* __restrict__ W,
                     const float* __restrict__ bias, float* __restrict__ Y, int K, int F){
  int b = blockIdx.x, f = threadIdx.x;
  if (f >= F) return;
  const float* xr = X + (size_t)b*K;
  const float* wr = W + (size_t)f*K;
  float acc = bias[f];
  for (int k = 0; k < K; ++k) acc = fmaf(xr[k], wr[k], acc);
  Y[(size_t)b*F + f] = acc;
}
__global__ void k_fc_out(const float* __restrict__ z2, const float* __restrict__ w,
                         const float* __restrict__ bias, float* __restrict__ out){
  int b = blockIdx.x*blockDim.x + threadIdx.x;
  if (b >= 256) return;
  float acc = bias[0];
  #pragma unroll
  for (int k = 0; k < 64; ++k) acc = fmaf(z2[b*64 + k], w[k], acc);
  out[b] = acc;
}

extern "C" void kernel_launch(void* const* d_in, const int* in_sizes, int n_in,
                              void* d_out, int out_size, void* d_ws, size_t ws_size,
                              hipStream_t stream) {
  const float* x_in     = (const float*)d_in[0];
  const float* edge_attr= (const float*)d_in[1];
  const float* conv_w   = (const float*)d_in[2];
  const float* conv_wih = (const float*)d_in[3];
  const float* conv_whh = (const float*)d_in[4];
  const float* conv_bih = (const float*)d_in[5];
  const float* conv_bhh = (const float*)d_in[6];
  const float* conv_nt  = (const float*)d_in[7];
  const float* s1_wih0 = (const float*)d_in[8];
  const float* s1_whh0 = (const float*)d_in[9];
  const float* s1_b0   = (const float*)d_in[10];
  const float* s1_wih1 = (const float*)d_in[11];
  const float* s1_whh1 = (const float*)d_in[12];
  const float* s1_b1   = (const float*)d_in[13];
  const float* s2_wih0 = (const float*)d_in[14];
  const float* s2_whh0 = (const float*)d_in[15];
  const float* s2_b0   = (const float*)d_in[16];
  const float* s2_wih1 = (const float*)d_in[17];
  const float* s2_whh1 = (const float*)d_in[18];
  const float* s2_b1   = (const float*)d_in[19];
  const float* bn_g    = (const float*)d_in[20];
  const float* bn_b    = (const float*)d_in[21];
  const float* prebn_g = (const float*)d_in[22];
  const float* prebn_b = (const float*)d_in[23];
  const float* fc_w0   = (const float*)d_in[24];
  const float* fc_b0   = (const float*)d_in[25];
  const float* fc_w1   = (const float*)d_in[26];
  const float* fc_b1   = (const float*)d_in[27];
  const float* fc_w2   = (const float*)d_in[28];
  const float* fc_b2   = (const float*)d_in[29];
  const float* fcbn_g0 = (const float*)d_in[30];
  const float* fcbn_b0 = (const float*)d_in[31];
  const float* fcbn_g1 = (const float*)d_in[32];
  const float* fcbn_b1 = (const float*)d_in[33];
  const int* edge_index   = (const int*)d_in[34];
  const int* node_type    = (const int*)d_in[35];
  const int* batch        = (const int*)d_in[36];
  const int* assign_src   = (const int*)d_in[37];
  const int* assign_dst   = (const int*)d_in[38];
  const int* edge_index_2 = (const int*)d_in[39];
  const int* batch_2      = (const int*)d_in[40];
  (void)in_sizes; (void)n_in; (void)out_size; (void)ws_size;

  // dynamic-LDS opt-ins (host-side, graph-capture-safe). 96KB proven r6;
  // 128KB = 96KB weights + 32KB wave-private staging (160KB/CU cap).
  int fused_ok = (hipFuncSetAttribute((const void*)k_gru_fused,
                    hipFuncAttributeMaxDynamicSharedMemorySize, 131072) == hipSuccess);
  int tr4_ok = (hipFuncSetAttribute((const void*)k_tr4d,
                    hipFuncAttributeMaxDynamicSharedMemorySize, 65536) == hipSuccess);

  // ---- workspace layout ----
  float* Wp = (float*)d_ws;
  size_t o = 0;
  auto alloc = [&](size_t n){ float* p = Wp + o; o += n; return p; };
  float* h     = alloc((size_t)NN1*64);
  float* tr    = alloc((size_t)4*NN1*64);   // tr slabs; gi slabs in GRU fallback
  float* aggr  = alloc((size_t)NN1*64);
  float* coeff = alloc(NN1);
  float* h2    = alloc((size_t)NN2*64);
  float* cnt   = alloc(NN2);
  float* x1    = alloc(256*128);
  float* x2    = alloc(256*128);
  float* z     = alloc(256*256);
  float* z1    = alloc(256*128);
  float* z2    = alloc(256*64);
  float* stats = alloc(128);
  float* w4    = alloc(245760);
  float* wihT  = alloc(61440);
  float* wihW  = alloc(61440);
  float* whh4  = alloc(61440);
  float* s2sT1 = alloc(81920);
  float* s2sT2 = alloc(81920);
  int* etype = (int*)alloc(EE1);
  int* cnt1  = (int*)alloc(NN1);
  int* R1    = (int*)alloc(NN1 + 1);
  int* ep1   = (int*)alloc(EE1);
  int* cnt2  = (int*)alloc(NN2);
  int* R2    = (int*)alloc(NN2 + 1);
  int* ep2   = (int*)alloc(EE2);
  int* csum  = (int*)alloc(260);
  int* rb1   = (int*)alloc(257);
  int* rb2   = (int*)alloc(257);

  const int* src1 = edge_index;
  const int* dst1 = edge_index + EE1;
  const int* src2 = edge_index_2;
  const int* dst2 = edge_index_2 + EE2;

  k_etype<<<(EE1+255)/256, 256, 0, stream>>>(edge_attr, etype, EE1);
  k_copy<<<(NN1*64+255)/256, 256, 0, stream>>>(x_in, h, NN1*64);
  k_prep_msgw<<<(245760+255)/256, 256, 0, stream>>>(conv_w, w4);
  k_prep_gruw<<<(61440+255)/256, 256, 0, stream>>>(conv_wih, conv_whh, wihT, wihW, whh4);
  k_s2strans<<<(81920+255)/256, 256, 0, stream>>>(s1_wih0, s1_whh0, s1_wih1, s1_whh1, s2sT1);
  k_s2strans<<<(81920+255)/256, 256, 0, stream>>>(s2_wih0, s2_whh0, s2_wih1, s2_whh1, s2sT2);
  k_batchptr<<<(NN1+255)/256, 256, 0, stream>>>(batch, rb1, NN1, 256);
  k_batchptr<<<(NN2+255)/256, 256, 0, stream>>>(batch_2, rb2, NN2, 256);

  {  // level-1 CSR (keys = dst; ep stores packed row index t*NN1+src)
    int M = NN1, nchunk = (M + 1023)/1024;
    hipMemsetAsync(cnt1, 0, (size_t)M*sizeof(int), stream);
    k_hist<<<(EE1+255)/256, 256, 0, stream>>>(dst1, cnt1, EE1);
    k_chunksum<<<nchunk, 256, 0, stream>>>(cnt1, csum, M);
    k_chunkscan<<<1, 256, 0, stream>>>(csum, nchunk);
    k_chunkapply<<<nchunk, 256, 0, stream>>>(cnt1, csum, R1, cnt1, M);
    k_scatter<<<(EE1+255)/256, 256, 0, stream>>>(src1, dst1, etype, cnt1, ep1, EE1, NN1);
  }
  {  // level-2 CSR (single type: ep = src)
    int M = NN2, nchunk = (M + 1023)/1024;
    hipMemsetAsync(cnt2, 0, (size_t)M*sizeof(int), stream);
    k_hist<<<(EE2+255)/256, 256, 0, stream>>>(dst2, cnt2, EE2);
    k_chunksum<<<nchunk, 256, 0, stream>>>(cnt2, csum, M);
    k_chunkscan<<<1, 256, 0, stream>>>(csum, nchunk);
    k_chunkapply<<<nchunk, 256, 0, stream>>>(cnt2, csum, R2, cnt2, M);
    k_scatter<<<(EE2+255)/256, 256, 0, stream>>>(src2, dst2, nullptr, cnt2, ep2, EE2, NN2);
  }

  // GRU: fused (gi+gh+pointwise, 128KB LDS) or fallback (tr3 + finW)
  auto gru = [&](float* hbuf, int N, int lidx){
    if (fused_ok){
      k_gru_fused<<<256, 1024, 131072, stream>>>(aggr, hbuf,
          wihW + (size_t)lidx*12288, whh4 + (size_t)lidx*12288,
          conv_bih + lidx*192, conv_bhh + lidx*192, N);
    } else {
      k_tr3<<<768, 256, 0, stream>>>(aggr, wihT + (size_t)lidx*12288, tr, N);
      k_gru_finW<<<768, 256, 0, stream>>>(tr, hbuf, whh4 + (size_t)lidx*12288,
          conv_bih + lidx*192, conv_bhh + lidx*192, N);
    }
  };

  // ---- level-1: 3x MGGC(L=3) + BN + ReLU ----
  for (int i = 0; i < 3; ++i){
    k_coeff<<<(NN1+255)/256, 256, 0, stream>>>(conv_nt + i*9, node_type, coeff, NN1);
    for (int l = 0; l < 3; ++l){
      const float* W4l = w4 + (size_t)(i*3+l)*16384;   // 4 matrices, float4 layout
      if (tr4_ok){
        k_tr4d<<<512, 1024, 65536, stream>>>(h, W4l, coeff, tr, NN1);
      } else {
        for (int t = 0; t < 4; ++t)
          k_tr1<<<1024, 256, 0, stream>>>(h, W4l + (size_t)t*4096, coeff,
                                          tr + (size_t)t*NN1*64, NN1);
      }
      k_sweep_p<<<(NN1+3)/4, 256, 0, stream>>>(tr, R1, ep1, aggr, NN1);
      gru(h, NN1, i);
    }
    hipMemsetAsync(stats, 0, 128*sizeof(float), stream);
    k_bnstats<<<256, 256, 0, stream>>>(h, stats, NN1);
    k_bnapply<<<(NN1*64+255)/256, 256, 0, stream>>>(h, stats, bn_g + i*64, bn_b + i*64, NN1, 1);
  }

  // ---- set2set (single fused kernel, 1024 threads/graph) ----
  k_set2set<<<256, 1024, 0, stream>>>(h, rb1, s2sT1, s1_b0, s1_b1, x1);

  // ---- avg_pool ----
  hipMemsetAsync(h2, 0, (size_t)NN2*64*sizeof(float), stream);
  hipMemsetAsync(cnt, 0, (size_t)NN2*sizeof(float), stream);
  k_pool_acc<<<(AA*64+255)/256, 256, 0, stream>>>(h, assign_src, assign_dst, h2, cnt, AA);
  k_pool_div<<<(NN2*64+255)/256, 256, 0, stream>>>(h2, cnt, NN2);

  // ---- level-2: 2x relu(MGGC(L=3)), only edge type 0 ----
  for (int L = 3; L < 5; ++L){
    for (int l = 0; l < 3; ++l){
      const float* W4l = w4 + (size_t)(L*3+l)*16384;   // t=0 slice used
      k_tr1<<<1250, 256, 0, stream>>>(h2, W4l, nullptr, tr, NN2);
      k_sweep_p<<<(NN2+3)/4, 256, 0, stream>>>(tr, R2, ep2, aggr, NN2);
      gru(h2, NN2, L);
    }
    k_relu<<<(NN2*64+255)/256, 256, 0, stream>>>(h2, NN2*64);
  }

  k_set2set<<<256, 1024, 0, stream>>>(h2, rb2, s2sT2, s2_b0, s2_b1, x2);

  // ---- head ----
  k_concat<<<256, 256, 0, stream>>>(x1, x2, z);
  k_bn_par<<<256, 256, 0, stream>>>(z, prebn_g, prebn_b, 256, 0);
  k_fc<<<256, 128, 0, stream>>>(z, fc_w0, fc_b0, z1, 256, 128);
  k_bn_par<<<128, 256, 0, stream>>>(z1, fcbn_g0, fcbn_b0, 128, 1);
  k_fc<<<256, 64, 0, stream>>>(z1, fc_w1, fc_b1, z2, 128, 64);
  k_bn_par<<<64, 256, 0, stream>>>(z2, fcbn_g1, fcbn_b1, 64, 1);
  k_fc_out<<<4, 64, 0, stream>>>(z2, fc_w2, fc_b2, (float*)d_out);
}

// Round 12
// 2031.893 us; speedup vs baseline: 1.3935x; 1.0014x over previous
//
#include <hip/hip_runtime.h>

#define NN1 60000
#define EE1 600000
#define NN2 20000
#define EE2 150000
#define AA  60000

__device__ __forceinline__ float sigf(float x){ return 1.f/(1.f+expf(-x)); }
// wave-uniform broadcast of lane sl's value. sl may be a RUNTIME uniform
// (v_readlane_b32 takes an SGPR lane index), so loops need not unroll.
__device__ __forceinline__ float rlane(float v, int sl){
  return __int_as_float(__builtin_amdgcn_readlane(__float_as_int(v), sl));
}
// Broadcast 4 channels (ld.x..ld.w) of lane SL, then FMA into named scalars.
// ALL state is named scalars -> guaranteed VGPRs (rounds 1/3: arrays spill).
#define RL4(SL) hx = rlane(ld.x, SL); hy = rlane(ld.y, SL); hz = rlane(ld.z, SL); hw = rlane(ld.w, SL);
#define FMA4(A, W) A = fmaf(hx, W.x, A); A = fmaf(hy, W.y, A); A = fmaf(hz, W.z, A); A = fmaf(hw, W.w, A);

// ---------- elementwise ----------
__global__ void k_relu(float* a, int n){
  int i = blockIdx.x*blockDim.x + threadIdx.x;
  if (i < n) a[i] = fmaxf(a[i], 0.f);
}
__global__ void k_copy(const float* __restrict__ a, float* __restrict__ o, int n){
  int i = blockIdx.x*blockDim.x + threadIdx.x;
  if (i < n) o[i] = a[i];
}

// ---------- edge type ----------
__global__ void k_etype(const float* __restrict__ ea, int* __restrict__ etype, int E){
  int e = blockIdx.x*blockDim.x + threadIdx.x;
  if (e >= E) return;
  const float* p = ea + (size_t)e*10;
  float best = p[0]; int bi = 0;
  #pragma unroll
  for (int k = 1; k < 4; ++k){ float v = p[k]; if (v > best){ best = v; bi = k; } }
  etype[e] = bi;
}

__global__ void k_coeff(const float* __restrict__ nt, const int* __restrict__ node_type,
                        float* __restrict__ coeff, int N){
  int n = blockIdx.x*blockDim.x + threadIdx.x;
  if (n < N) coeff[n] = nt[node_type[n]];
}

// ---------- batch row pointers (batch sorted ascending) ----------
__global__ void k_batchptr(const int* __restrict__ batch, int* __restrict__ rb, int N, int B){
  int n = blockIdx.x*blockDim.x + threadIdx.x;
  if (n >= N) return;
  int b = batch[n];
  if (n == 0){ for (int g = 0; g <= b; ++g) rb[g] = 0; }
  else {
    int pb = batch[n-1];
    for (int g = pb+1; g <= b; ++g) rb[g] = n;
  }
  if (n == N-1){ for (int g = b+1; g <= B; ++g) rb[g] = N; }
}

// ---------- weight prep ----------
// msg weights: conv_w[m][c][d] (m = (li*3+l)*4+t) -> w4[m][c4][d][q],
// float4 element (c4,d) = { W[4c4+0][d], W[4c4+1][d], W[4c4+2][d], W[4c4+3][d] }.
// In-kernel lane d reads float4 index c4*64+d: contiguous -> conflict-free b128.
__global__ void k_prep_msgw(const float* __restrict__ w, float* __restrict__ w4){
  int idx = blockIdx.x*256 + threadIdx.x;   // 60*4096 = 245760
  if (idx >= 245760) return;
  int m = idx >> 12, r = idx & 4095;
  int c4 = r >> 8, d = (r >> 2) & 63, q = r & 3;
  w4[idx] = w[m*4096 + (4*c4+q)*64 + d];
}
// GRU weights, three layouts:
//  wihT[l][t][c4][d][q] = wih[l][(64t+d)][4c4+q]  (tr3 fallback: lane d owns row 64t+d)
//  wihW[l][c4][j][q]    = wih[l][j][4c4+q]        (fused: lane l owns rows {l,64+l,128+l})
//  whh4[l][c4][j][q]    = whh[l][j][4c4+q]
__global__ void k_prep_gruw(const float* __restrict__ wih, const float* __restrict__ whh,
                            float* __restrict__ wihT, float* __restrict__ wihW,
                            float* __restrict__ whh4){
  int idx = blockIdx.x*256 + threadIdx.x;   // 5*12288 = 61440 each
  if (idx >= 61440) return;
  {
    int l = idx / 12288, r = idx % 12288;
    int t = r >> 12, rr = r & 4095;
    int c4 = rr >> 8, d = (rr >> 2) & 63, q = rr & 3;
    wihT[idx] = wih[l*12288 + (64*t + d)*64 + 4*c4 + q];
  }
  {
    int l = idx / 12288, rr = idx % 12288;
    int e = rr >> 2, q = rr & 3;
    int c4 = e / 192, j = e - c4*192;
    wihW[idx] = wih[l*12288 + j*64 + 4*c4 + q];
    whh4[idx] = whh[l*12288 + j*64 + 4*c4 + q];
  }
}

// ---------- set2set LSTM weight transpose to [k][j] (coalesced over gate row j) ----------
__global__ void k_s2strans(const float* __restrict__ wih0, const float* __restrict__ whh0,
                           const float* __restrict__ wih1, const float* __restrict__ whh1,
                           float* __restrict__ T){
  int idx = blockIdx.x*256 + threadIdx.x;
  if (idx < 32768){ int k = idx >> 8, j = idx & 255; T[idx] = wih0[j*128 + k]; }
  else if (idx < 49152){ int r = idx - 32768; int k = r >> 8, j = r & 255; T[idx] = whh0[j*64 + k]; }
  else if (idx < 65536){ int r = idx - 49152; int k = r >> 8, j = r & 255; T[idx] = wih1[j*64 + k]; }
  else if (idx < 81920){ int r = idx - 65536; int k = r >> 8, j = r & 255; T[idx] = whh1[j*64 + k]; }
}

// ---------- CSR build ----------
__global__ void k_hist(const int* __restrict__ dst, int* __restrict__ cnt, int E){
  int e = blockIdx.x*blockDim.x + threadIdx.x;
  if (e >= E) return;
  atomicAdd(&cnt[dst[e]], 1);
}
__global__ void k_chunksum(const int* __restrict__ cnt, int* __restrict__ csum, int M){
  __shared__ int sh[256];
  int base = blockIdx.x*1024;
  int s = 0;
  for (int i = threadIdx.x; i < 1024; i += 256){
    int idx = base + i;
    if (idx < M) s += cnt[idx];
  }
  sh[threadIdx.x] = s;
  __syncthreads();
  for (int o = 128; o; o >>= 1){
    if (threadIdx.x < o) sh[threadIdx.x] += sh[threadIdx.x + o];
    __syncthreads();
  }
  if (threadIdx.x == 0) csum[blockIdx.x] = sh[0];
}
__global__ void k_chunkscan(int* __restrict__ csum, int nchunk){
  __shared__ int sh[256];
  int i = threadIdx.x;
  int v = (i < nchunk) ? csum[i] : 0;
  sh[i] = v; __syncthreads();
  for (int o = 1; o < 256; o <<= 1){
    int y = (i >= o) ? sh[i-o] : 0;
    __syncthreads();
    sh[i] += y;
    __syncthreads();
  }
  if (i < nchunk) csum[i] = sh[i] - v;
  if (i == 255) csum[nchunk] = sh[255];
}
__global__ void k_chunkapply(const int* __restrict__ cnt, const int* __restrict__ csum,
                             int* __restrict__ R, int* __restrict__ cur, int M){
  __shared__ int sh[256];
  int base = blockIdx.x*1024;
  int i0 = base + threadIdx.x*4;
  int v[4]; int s = 0;
  #pragma unroll
  for (int k = 0; k < 4; ++k){ int idx = i0 + k; v[k] = (idx < M) ? cnt[idx] : 0; s += v[k]; }
  sh[threadIdx.x] = s; __syncthreads();
  for (int o = 1; o < 256; o <<= 1){
    int y = (threadIdx.x >= o) ? sh[threadIdx.x-o] : 0;
    __syncthreads();
    sh[threadIdx.x] += y;
    __syncthreads();
  }
  int run = csum[blockIdx.x] + sh[threadIdx.x] - s;
  #pragma unroll
  for (int k = 0; k < 4; ++k){
    int idx = i0 + k;
    if (idx < M){ R[idx] = run; cur[idx] = run; run += v[k]; }
  }
  if (threadIdx.x == 255 && base + 1024 >= M) R[M] = csum[blockIdx.x] + sh[255];
}
// scatter packs the FULL tr row index (t*N + src, < 2^31) so the sweep's
// per-edge address math is a single shift.
__global__ void k_scatter(const int* __restrict__ src, const int* __restrict__ dst,
                          const int* __restrict__ etype, int* __restrict__ cur,
                          int* __restrict__ ep, int E, int N){
  int e = blockIdx.x*blockDim.x + threadIdx.x;
  if (e >= E) return;
  int t = etype ? etype[e] : 0;
  int pos = atomicAdd(&cur[dst[e]], 1);
  ep[pos] = t*N + src[e];
}

// ---------- dense transforms: LDS weights + 1 coalesced load + readlane ----------
// tr[t][n][d] = coeff[n] * sum_c h[n][c]*W[t][c][d].
// Per 4-node group: ONE dwordx4/wave; readlane broadcasts; NAMED-SCALAR
// accumulators (arrays spill: r1/r3). Weights in LDS, conflict-free b128.
// r12: register PREFETCH of the next group's tile — the load for g+stride is
// issued before the c4 loop, so its latency hides under the current compute
// (was exposed ~200-600cy per group).

// 4 matrices in one pass: 64 KB LDS, 1024 thr, rl:fma = 1:4.  [r8: -440us]
__global__ __launch_bounds__(1024, 4) void k_tr4d(
    const float* __restrict__ h, const float* __restrict__ W4,
    const float* __restrict__ coeff, float* __restrict__ tr, int N){
  extern __shared__ float4 wl[];           // [4][1024] = 64 KB
  for (int i = threadIdx.x; i < 4096; i += 1024) wl[i] = ((const float4*)W4)[i];
  __syncthreads();
  int lane = threadIdx.x & 63, wv = threadIdx.x >> 6;   // 16 waves
  int ng = N >> 2, stride = gridDim.x*16;
  int g0 = blockIdx.x*16 + wv;
  float4 ld;
  if (g0 < ng) ld = ((const float4*)(h + ((size_t)(g0 << 2) << 6)))[lane];
  for (int g = g0; g < ng; g += stride){
    int n0 = g << 2;
    int gn = g + stride;
    float4 ldn = ld;
    if (gn < ng) ldn = ((const float4*)(h + ((size_t)(gn << 2) << 6)))[lane];
    float a00=0.f,a01=0.f,a02=0.f,a03=0.f;
    float a10=0.f,a11=0.f,a12=0.f,a13=0.f;
    float a20=0.f,a21=0.f,a22=0.f,a23=0.f;
    float a30=0.f,a31=0.f,a32=0.f,a33=0.f;
    for (int c4 = 0; c4 < 16; ++c4){
      int wb = (c4 << 6) + lane;
      float4 w0 = wl[wb], w1 = wl[1024+wb], w2 = wl[2048+wb], w3 = wl[3072+wb];
      float hx, hy, hz, hw;
      RL4(c4)     FMA4(a00,w0) FMA4(a10,w1) FMA4(a20,w2) FMA4(a30,w3)
      RL4(16|c4)  FMA4(a01,w0) FMA4(a11,w1) FMA4(a21,w2) FMA4(a31,w3)
      RL4(32|c4)  FMA4(a02,w0) FMA4(a12,w1) FMA4(a22,w2) FMA4(a32,w3)
      RL4(48|c4)  FMA4(a03,w0) FMA4(a13,w1) FMA4(a23,w2) FMA4(a33,w3)
    }
    float4 cv = ((const float4*)coeff)[g];
    a00*=cv.x; a01*=cv.y; a02*=cv.z; a03*=cv.w;
    a10*=cv.x; a11*=cv.y; a12*=cv.z; a13*=cv.w;
    a20*=cv.x; a21*=cv.y; a22*=cv.z; a23*=cv.w;
    a30*=cv.x; a31*=cv.y; a32*=cv.z; a33*=cv.w;
    float* o0 = tr + ((size_t)n0 << 6) + lane;
    o0[0]=a00; o0[64]=a01; o0[128]=a02; o0[192]=a03;
    float* o1 = tr + (((size_t)N + n0) << 6) + lane;
    o1[0]=a10; o1[64]=a11; o1[128]=a12; o1[192]=a13;
    float* o2 = tr + (((size_t)2*N + n0) << 6) + lane;
    o2[0]=a20; o2[64]=a21; o2[128]=a22; o2[192]=a23;
    float* o3 = tr + (((size_t)3*N + n0) << 6) + lane;
    o3[0]=a30; o3[64]=a31; o3[128]=a32; o3[192]=a33;
    ld = ldn;
  }
}

// single-matrix variant (level-2; also tr4d fallback), 16 KB static LDS
__global__ __launch_bounds__(256) void k_tr1(
    const float* __restrict__ h, const float* __restrict__ W4,
    const float* __restrict__ coeff, float* __restrict__ tr, int N){
  __shared__ float4 wl[1024];                 // 16 KB
  for (int i = threadIdx.x; i < 1024; i += 256) wl[i] = ((const float4*)W4)[i];
  __syncthreads();
  int lane = threadIdx.x & 63, w = threadIdx.x >> 6;
  int ng = N >> 2, stride = gridDim.x*4;
  int g0 = blockIdx.x*4 + w;
  float4 ld;
  if (g0 < ng) ld = ((const float4*)(h + ((size_t)(g0 << 2) << 6)))[lane];
  for (int g = g0; g < ng; g += stride){
    int n0 = g << 2;
    int gn = g + stride;
    float4 ldn = ld;
    if (gn < ng) ldn = ((const float4*)(h + ((size_t)(gn << 2) << 6)))[lane];
    float a0=0.f, a1=0.f, a2=0.f, a3=0.f;
    for (int c4 = 0; c4 < 16; ++c4){
      float4 w0 = wl[(c4 << 6) + lane];
      float hx, hy, hz, hw;
      RL4(c4)       FMA4(a0, w0)
      RL4(16|c4)    FMA4(a1, w0)
      RL4(32|c4)    FMA4(a2, w0)
      RL4(48|c4)    FMA4(a3, w0)
    }
    if (coeff){
      float4 cv = ((const float4*)coeff)[g];
      a0 *= cv.x; a1 *= cv.y; a2 *= cv.z; a3 *= cv.w;
    }
    float* o0 = tr + ((size_t)n0 << 6) + lane;
    o0[0] = a0; o0[64] = a1; o0[128] = a2; o0[192] = a3;
    ld = ldn;
  }
}

// ---------- merged sweep (gather tr rows per dst via CSR) ----------
// ep holds the packed row index (t*N+src) -> addr = (ridx<<6)+lane.
// 4-unroll with 4 independent accumulators: 4 gathers in flight per wave.
__global__ void k_sweep_p(const float* __restrict__ tr, const int* __restrict__ R,
                          const int* __restrict__ ep, float* __restrict__ aggr, int N){
  int w = threadIdx.x >> 6, lane = threadIdx.x & 63;
  int d = blockIdx.x*4 + w;
  if (d >= N) return;
  int p = R[d], pend = R[d+1];
  float a0=0.f, a1=0.f, a2=0.f, a3=0.f;
  while (p < pend){
    int m = pend - p; if (m > 64) m = 64;
    int ev = (lane < m) ? ep[p + lane] : 0;
    int j = 0;
    for (; j + 4 <= m; j += 4){
      int r0 = __shfl(ev, j),   r1 = __shfl(ev, j+1);
      int r2 = __shfl(ev, j+2), r3 = __shfl(ev, j+3);
      float v0 = tr[((size_t)r0 << 6) + lane];
      float v1 = tr[((size_t)r1 << 6) + lane];
      float v2 = tr[((size_t)r2 << 6) + lane];
      float v3 = tr[((size_t)r3 << 6) + lane];
      a0 += v0; a1 += v1; a2 += v2; a3 += v3;
    }
    for (; j < m; ++j){
      int r0 = __shfl(ev, j);
      a0 += tr[((size_t)r0 << 6) + lane];
    }
    p += m;
  }
  aggr[(size_t)d*64 + lane] = (a0 + a1) + (a2 + a3);
}

// ---------- tr3: GRU-fallback gi transform (LDS weights + readlane) ----------
__global__ __launch_bounds__(256) void k_tr3(
    const float* __restrict__ h, const float* __restrict__ W4,
    float* __restrict__ tr, int N){
  __shared__ float4 wl[3072];                 // 48 KB (3 matrices)
  for (int i = threadIdx.x; i < 3072; i += 256) wl[i] = ((const float4*)W4)[i];
  __syncthreads();
  int lane = threadIdx.x & 63, w = threadIdx.x >> 6;
  int ng = N >> 2, stride = gridDim.x*4;
  for (int g = blockIdx.x*4 + w; g < ng; g += stride){
    int n0 = g << 2;
    float4 ld = ((const float4*)(h + ((size_t)n0 << 6)))[lane];
    float a00=0.f,a01=0.f,a02=0.f,a03=0.f;
    float a10=0.f,a11=0.f,a12=0.f,a13=0.f;
    float a20=0.f,a21=0.f,a22=0.f,a23=0.f;
    for (int c4 = 0; c4 < 16; ++c4){
      float4 w0 = wl[(c4 << 6) + lane];
      float4 w1 = wl[1024 + (c4 << 6) + lane];
      float4 w2 = wl[2048 + (c4 << 6) + lane];
      float hx, hy, hz, hw;
      RL4(c4)       FMA4(a00, w0) FMA4(a10, w1) FMA4(a20, w2)
      RL4(16|c4)    FMA4(a01, w0) FMA4(a11, w1) FMA4(a21, w2)
      RL4(32|c4)    FMA4(a02, w0) FMA4(a12, w1) FMA4(a22, w2)
      RL4(48|c4)    FMA4(a03, w0) FMA4(a13, w1) FMA4(a23, w2)
    }
    float* o0 = tr + ((size_t)n0 << 6) + lane;
    o0[0] = a00; o0[64] = a01; o0[128] = a02; o0[192] = a03;
    float* o1 = tr + (((size_t)N + n0) << 6) + lane;
    o1[0] = a10; o1[64] = a11; o1[128] = a12; o1[192] = a13;
    float* o2 = tr + (((size_t)2*N + n0) << 6) + lane;
    o2[0] = a20; o2[64] = a21; o2[128] = a22; o2[192] = a23;
  }
}

// ---------- fully fused GRU: both GEMVs + pointwise in ONE kernel ----------
// r11: broadcasts on the LDS pipe (wave-private staging). r12: register
// PREFETCH — next group's la/ld loads issue right after staging the current
// tile, so global latency (was exposed at each group top) hides under the
// 16-c4 compute. LDS 96KB weights + 32KB staging = 128KB, 1 block/CU.
#define GACC2(K, R, Z, P, Q) { \
  float4 av = stg[((K) << 4) + c4]; \
  float4 hv = stg[64 + ((K) << 4) + c4]; \
  R = fmaf(av.x,iwr.x,R); R = fmaf(av.y,iwr.y,R); R = fmaf(av.z,iwr.z,R); R = fmaf(av.w,iwr.w,R); \
  R = fmaf(hv.x,hwr.x,R); R = fmaf(hv.y,hwr.y,R); R = fmaf(hv.z,hwr.z,R); R = fmaf(hv.w,hwr.w,R); \
  Z = fmaf(av.x,iwz.x,Z); Z = fmaf(av.y,iwz.y,Z); Z = fmaf(av.z,iwz.z,Z); Z = fmaf(av.w,iwz.w,Z); \
  Z = fmaf(hv.x,hwz.x,Z); Z = fmaf(hv.y,hwz.y,Z); Z = fmaf(hv.z,hwz.z,Z); Z = fmaf(hv.w,hwz.w,Z); \
  P = fmaf(av.x,iwn.x,P); P = fmaf(av.y,iwn.y,P); P = fmaf(av.z,iwn.z,P); P = fmaf(av.w,iwn.w,P); \
  Q = fmaf(hv.x,hwn.x,Q); Q = fmaf(hv.y,hwn.y,Q); Q = fmaf(hv.z,hwn.z,Q); Q = fmaf(hv.w,hwn.w,Q); }
#define GFIN(K, R, Z, P, Q) { \
    size_t off = base + ((size_t)(K) << 6) + lane; \
    float hv = h[off]; \
    float r = sigf(R), z = sigf(Z); \
    float nn = tanhf(P + r*Q); \
    h[off] = (1.f - z)*nn + z*hv; }
__global__ __launch_bounds__(1024, 4) void k_gru_fused(
    const float* __restrict__ aggr, float* __restrict__ h,
    const float* __restrict__ wihW, const float* __restrict__ whhW,
    const float* __restrict__ bih, const float* __restrict__ bhh, int N){
  extern __shared__ float4 wl[];           // [6144 w] + [16][128] staging = 128 KB
  for (int i = threadIdx.x; i < 6144; i += 1024)
    wl[i] = (i < 3072) ? ((const float4*)wihW)[i] : ((const float4*)whhW)[i - 3072];
  __syncthreads();
  const float4* wi = wl;
  const float4* wh = wl + 3072;
  int lane = threadIdx.x & 63, wv = threadIdx.x >> 6;
  float4* stg = wl + 6144 + wv*128;        // wave-private: [0..63]=la, [64..127]=ld
  float br  = bih[lane]     + bhh[lane];
  float bz  = bih[64+lane]  + bhh[64+lane];
  float bp  = bih[128+lane];                // gi_n bias
  float bq  = bhh[128+lane];                // gh_n bias
  int ng = N >> 2, stride = gridDim.x*16;
  int g0 = blockIdx.x*16 + wv;
  float4 la, ld;
  if (g0 < ng){
    size_t b0_ = (size_t)(g0 << 2) << 6;
    la = ((const float4*)(aggr + b0_))[lane];
    ld = ((const float4*)(h + b0_))[lane];
  }
  for (int g = g0; g < ng; g += stride){
    int n0 = g << 2;
    size_t base = (size_t)n0 << 6;
    stg[lane] = la;
    stg[64 + lane] = ld;
    int gn = g + stride;
    float4 la2 = la, ld2 = ld;
    if (gn < ng){
      size_t bn = (size_t)(gn << 2) << 6;
      la2 = ((const float4*)(aggr + bn))[lane];
      ld2 = ((const float4*)(h + bn))[lane];
    }
    float r0=br, r1=br, r2=br, r3=br;
    float z0=bz, z1=bz, z2=bz, z3=bz;
    float p0=bp, p1=bp, p2=bp, p3=bp;
    float q0=bq, q1=bq, q2=bq, q3=bq;
    for (int c4 = 0; c4 < 16; ++c4){
      int wb = c4*192 + lane;
      float4 iwr = wi[wb], iwz = wi[wb+64], iwn = wi[wb+128];
      float4 hwr = wh[wb], hwz = wh[wb+64], hwn = wh[wb+128];
      GACC2(0, r0, z0, p0, q0)
      GACC2(1, r1, z1, p1, q1)
      GACC2(2, r2, z2, p2, q2)
      GACC2(3, r3, z3, p3, q3)
    }
    GFIN(0, r0, z0, p0, q0)
    GFIN(1, r1, z1, p1, q1)
    GFIN(2, r2, z2, p2, q2)
    GFIN(3, r3, z3, p3, q3)
    la = la2; ld = ld2;
  }
}

// ---------- GRU finalize fallback (used only if 128KB dynamic LDS refused) ----------
#define GRUACC(SL, RK, ZK, NK) RL4(SL) FMA4(RK, wr) FMA4(ZK, wz) FMA4(NK, wn)
#define GRUFIN(K, RK, ZK, NK) { \
    size_t off = base + (K << 6) + lane; \
    float gir = gi[off], giz = gi[S + off], gin = gi[2*S + off]; \
    float hv = h[off]; \
    float r = sigf(gir + bir + RK); \
    float z = sigf(giz + biz + ZK); \
    float nv = tanhf(gin + bin_ + r*NK); \
    h[off] = (1.f - z)*nv + z*hv; }
__global__ __launch_bounds__(256, 3) void k_gru_finW(
    const float* __restrict__ gi, float* __restrict__ h,
    const float* __restrict__ whh4,
    const float* __restrict__ bih, const float* __restrict__ bhh, int N){
  __shared__ float4 wh[3072];              // [c4][192] = whh[j][4c4+q], 48KB
  for (int i = threadIdx.x; i < 3072; i += 256) wh[i] = ((const float4*)whh4)[i];
  __syncthreads();
  int lane = threadIdx.x & 63, w = threadIdx.x >> 6;
  float bir = bih[lane], biz = bih[64+lane], bin_ = bih[128+lane];
  float bhr = bhh[lane], bhz = bhh[64+lane], bhn = bhh[128+lane];
  size_t S = (size_t)N << 6;
  int ng = N >> 2, stride = gridDim.x*4;
  for (int g = blockIdx.x*4 + w; g < ng; g += stride){
    int n0 = g << 2;
    size_t base = (size_t)n0 << 6;
    float4 ld = ((const float4*)(h + base))[lane];
    float ar0=bhr, ar1=bhr, ar2=bhr, ar3=bhr;
    float az0=bhz, az1=bhz, az2=bhz, az3=bhz;
    float an0=bhn, an1=bhn, an2=bhn, an3=bhn;
    for (int c4 = 0; c4 < 16; ++c4){
      int wb = c4*192 + lane;
      float4 wr = wh[wb];
      float4 wz = wh[wb + 64];
      float4 wn = wh[wb + 128];
      float hx, hy, hz, hw;
      GRUACC(c4,    ar0, az0, an0)
      GRUACC(16|c4, ar1, az1, an1)
      GRUACC(32|c4, ar2, az2, an2)
      GRUACC(48|c4, ar3, az3, an3)
    }
    GRUFIN(0, ar0, az0, an0)
    GRUFIN(1, ar1, az1, an1)
    GRUFIN(2, ar2, az2, an2)
    GRUFIN(3, ar3, az3, an3)
  }
}

// ---------- batch norm over nodes ----------
__global__ void k_bnstats(const float* __restrict__ h, float* __restrict__ stats, int N){
  int c = threadIdx.x & 63;
  int g = threadIdx.x >> 6;
  float s = 0.f, s2 = 0.f;
  for (int n = blockIdx.x*4 + g; n < N; n += gridDim.x*4){
    float v = h[(size_t)n*64 + c]; s += v; s2 += v*v;
  }
  __shared__ float sh[4][64], sh2[4][64];
  sh[g][c] = s; sh2[g][c] = s2;
  __syncthreads();
  if (g == 0){
    float ts = sh[0][c]+sh[1][c]+sh[2][c]+sh[3][c];
    float t2 = sh2[0][c]+sh2[1][c]+sh2[2][c]+sh2[3][c];
    atomicAdd(&stats[c], ts); atomicAdd(&stats[64+c], t2);
  }
}
__global__ void k_bnapply(float* __restrict__ h, const float* __restrict__ stats,
                          const float* __restrict__ g, const float* __restrict__ b,
                          int N, int relu){
  int i = blockIdx.x*blockDim.x + threadIdx.x;
  if (i >= N*64) return;
  int c = i & 63;
  float inv = 1.f/(float)N;
  float mean = stats[c]*inv;
  float var  = stats[64+c]*inv - mean*mean;
  float y = (h[i]-mean)*rsqrtf(var + 1e-5f)*g[c] + b[c];
  if (relu) y = fmaxf(y, 0.f);
  h[i] = y;
}

// ---------- avg_pool ----------
__global__ void k_pool_acc(const float* __restrict__ h, const int* __restrict__ asrc,
                           const int* __restrict__ adst, float* __restrict__ h2,
                           float* __restrict__ cnt, int A){
  int i = blockIdx.x*blockDim.x + threadIdx.x;
  if (i >= A*64) return;
  int a = i >> 6, c = i & 63;
  int s = asrc[a], d = adst[a];
  atomicAdd(&h2[(size_t)d*64 + c], h[(size_t)s*64 + c]);
  if (c == 0) atomicAdd(&cnt[d], 1.f);
}
__global__ void k_pool_div(float* __restrict__ h2, const float* __restrict__ cnt, int N){
  int i = blockIdx.x*blockDim.x + threadIdx.x;
  if (i >= N*64) return;
  h2[i] = h2[i] / fmaxf(cnt[i >> 6], 1.f);
}

// ---------- fully fused set2set: one block (1024 thr = 16 waves) per graph ----------
// r12: gate GEMVs use ALL 1024 threads (was j<256 only = 4 of 16 waves).
// Thread (part=j>>8, row=j&255) sums a quarter of the k-range into gp[4][256];
// the j<64 pointwise reduces the 4 partials per gate row. Loads/thread in the
// gate phase drop 320 -> 80. Attention stays online-softmax (r10).
__global__ __launch_bounds__(1024) void k_set2set(const float* __restrict__ x, const int* __restrict__ rb,
                          const float* __restrict__ T,
                          const float* __restrict__ b0, const float* __restrict__ b1,
                          float* __restrict__ xout){
  int b = blockIdx.x, j = threadIdx.x;
  int w = j >> 6, lane = j & 63;
  int part = j >> 8, row = j & 255;
  __shared__ float qstar[128], h0[64], c0[64], h1[64], c1[64];
  __shared__ float gp[4][256], wmax[16], wsum[16], racc[16][64];
  if (j < 128) qstar[j] = 0.f;
  if (j < 64){ h0[j] = 0.f; c0[j] = 0.f; h1[j] = 0.f; c1[j] = 0.f; }
  __syncthreads();
  int n0 = rb[b], n1 = rb[b+1];
  const float* T0 = T;            // wih0T [128][256]
  const float* T1 = T + 32768;    // whh0T [64][256]
  const float* T2 = T + 49152;    // wih1T [64][256]
  const float* T3 = T + 65536;    // whh1T [64][256]
  for (int s = 0; s < 5; ++s){
    {  // LSTM0 partials: part covers qstar[32p..32p+32) and h0[16p..16p+16)
      float a0 = 0.f, a1 = 0.f, a2 = 0.f, a3 = 0.f;
      int kq = part << 5;
      for (int k = kq; k < kq + 32; k += 4){
        a0 = fmaf(T0[(k+0)*256 + row], qstar[k+0], a0);
        a1 = fmaf(T0[(k+1)*256 + row], qstar[k+1], a1);
        a2 = fmaf(T0[(k+2)*256 + row], qstar[k+2], a2);
        a3 = fmaf(T0[(k+3)*256 + row], qstar[k+3], a3);
      }
      int kh = part << 4;
      for (int k = kh; k < kh + 16; k += 4){
        a0 = fmaf(T1[(k+0)*256 + row], h0[k+0], a0);
        a1 = fmaf(T1[(k+1)*256 + row], h0[k+1], a1);
        a2 = fmaf(T1[(k+2)*256 + row], h0[k+2], a2);
        a3 = fmaf(T1[(k+3)*256 + row], h0[k+3], a3);
      }
      gp[part][row] = (a0 + a1) + (a2 + a3);
    }
    __syncthreads();
    if (j < 64){
      float gi_ = b0[j]     + gp[0][j]     + gp[1][j]     + gp[2][j]     + gp[3][j];
      float gf  = b0[64+j]  + gp[0][64+j]  + gp[1][64+j]  + gp[2][64+j]  + gp[3][64+j];
      float gg  = b0[128+j] + gp[0][128+j] + gp[1][128+j] + gp[2][128+j] + gp[3][128+j];
      float go  = b0[192+j] + gp[0][192+j] + gp[1][192+j] + gp[2][192+j] + gp[3][192+j];
      float ig = sigf(gi_);
      float fg = sigf(gf);
      float ggt = tanhf(gg);
      float og = sigf(go);
      float cn = fg*c0[j] + ig*ggt;
      c0[j] = cn;
      h0[j] = og*tanhf(cn);
    }
    __syncthreads();
    {  // LSTM1 partials: part covers h0[16p..16p+16) and h1[16p..16p+16)
      float a0 = 0.f, a1 = 0.f, a2 = 0.f, a3 = 0.f;
      int kh = part << 4;
      for (int k = kh; k < kh + 16; k += 4){
        a0 = fmaf(T2[(k+0)*256 + row], h0[k+0], a0);
        a1 = fmaf(T2[(k+1)*256 + row], h0[k+1], a1);
        a2 = fmaf(T2[(k+2)*256 + row], h0[k+2], a2);
        a3 = fmaf(T2[(k+3)*256 + row], h0[k+3], a3);
      }
      for (int k = kh; k < kh + 16; k += 4){
        a0 = fmaf(T3[(k+0)*256 + row], h1[k+0], a0);
        a1 = fmaf(T3[(k+1)*256 + row], h1[k+1], a1);
        a2 = fmaf(T3[(k+2)*256 + row], h1[k+2], a2);
        a3 = fmaf(T3[(k+3)*256 + row], h1[k+3], a3);
      }
      gp[part][row] = (a0 + a1) + (a2 + a3);
    }
    __syncthreads();
    if (j < 64){
      float gi_ = b1[j]     + gp[0][j]     + gp[1][j]     + gp[2][j]     + gp[3][j];
      float gf  = b1[64+j]  + gp[0][64+j]  + gp[1][64+j]  + gp[2][64+j]  + gp[3][64+j];
      float gg  = b1[128+j] + gp[0][128+j] + gp[1][128+j] + gp[2][128+j] + gp[3][128+j];
      float go  = b1[192+j] + gp[0][192+j] + gp[1][192+j] + gp[2][192+j] + gp[3][192+j];
      float ig = sigf(gi_);
      float fg = sigf(gf);
      float ggt = tanhf(gg);
      float og = sigf(go);
      float cn = fg*c1[j] + ig*ggt;
      c1[j] = cn;
      float hn = og*tanhf(cn);
      h1[j] = hn;
      qstar[j] = hn;
    }
    __syncthreads();
    // ---- online-softmax attention: ONE pass over the graph's nodes ----
    float lmax = -3.4e38f, lsum = 0.f, lr = 0.f;
    for (int n = n0 + w; n < n1; n += 16){
      float xv = x[(size_t)n*64 + lane];
      float v = xv*qstar[lane];
      #pragma unroll
      for (int o = 32; o; o >>= 1) v += __shfl_xor(v, o);
      float nm = fmaxf(lmax, v);
      float corr = expf(lmax - nm);    // 0 on first node (lmax=-inf-ish)
      float e = expf(v - nm);
      lsum = fmaf(lsum, corr, e);
      lr   = fmaf(lr, corr, e*xv);
      lmax = nm;
    }
    if (lane == 0){ wmax[w] = lmax; wsum[w] = lsum; }
    racc[w][lane] = lr;
    __syncthreads();
    if (j < 64){
      float M = wmax[0];
      #pragma unroll
      for (int k = 1; k < 16; ++k) M = fmaxf(M, wmax[k]);
      float denom = 0.f, r = 0.f;
      #pragma unroll
      for (int k = 0; k < 16; ++k){
        float sc = expf(wmax[k] - M);  // 0 for empty waves
        denom = fmaf(wsum[k], sc, denom);
        r     = fmaf(racc[k][j], sc, r);
      }
      qstar[64 + j] = (denom > 0.f) ? (r/denom) : 0.f;
    }
    __syncthreads();
  }
  if (j < 128) xout[(size_t)b*128 + j] = qstar[j];
}

// ---------- head ----------
__global__ void k_concat(const float* __restrict__ x1, const float* __restrict__ x2,
                         float* __restrict__ z){
  int i = blockIdx.x*blockDim.x + threadIdx.x;
  if (i >= 256*256) return;
  int b = i >> 8, c = i & 255;
  z[i] = (c < 128) ? x1[b*128 + c] : x2[b*128 + (c - 128)];
}
__global__ void k_bn_par(float* __restrict__ X, const float* __restrict__ g,
                         const float* __restrict__ b, int F, int relu){
  int f = blockIdx.x, i = threadIdx.x;
  float v = X[(size_t)i*F + f];
  __shared__ float s1[256], s2[256];
  s1[i] = v; s2[i] = v*v;
  __syncthreads();
  for (int o = 128; o; o >>= 1){
    if (i < o){ s1[i] += s1[i+o]; s2[i] += s2[i+o]; }
    __syncthreads();
  }
  float mean = s1[0]*(1.f/256.f);
  float var  = s2[0]*(1.f/256.f) - mean*mean;
  float y = (v - mean)*rsqrtf(var + 1e-5f)*g[f] + b[f];
  if (relu) y = fmaxf(y, 0.f);
  X[(size_t)i*F + f] = y;
}
__global__ void k_fc(const float* __restrict__ X, const float* __restrict__ W,
                     const float* __restrict__ bias, float* __restrict__ Y, int K, int F){
  int b = blockIdx.x, f = threadIdx.x;
  if (f >= F) return;
  const float* xr = X + (size_t)b*K;
  const float* wr = W + (size_t)f*K;
  float acc = bias[f];
  for (int k = 0; k < K; ++k) acc = fmaf(xr[k], wr[k], acc);
  Y[(size_t)b*F + f] = acc;
}
__global__ void k_fc_out(const float* __restrict__ z2, const float* __restrict__ w,
                         const float* __restrict__ bias, float* __restrict__ out){
  int b = blockIdx.x*blockDim.x + threadIdx.x;
  if (b >= 256) return;
  float acc = bias[0];
  #pragma unroll
  for (int k = 0; k < 64; ++k) acc = fmaf(z2[b*64 + k], w[k], acc);
  out[b] = acc;
}

extern "C" void kernel_launch(void* const* d_in, const int* in_sizes, int n_in,
                              void* d_out, int out_size, void* d_ws, size_t ws_size,
                              hipStream_t stream) {
  const float* x_in     = (const float*)d_in[0];
  const float* edge_attr= (const float*)d_in[1];
  const float* conv_w   = (const float*)d_in[2];
  const float* conv_wih = (const float*)d_in[3];
  const float* conv_whh = (const float*)d_in[4];
  const float* conv_bih = (const float*)d_in[5];
  const float* conv_bhh = (const float*)d_in[6];
  const float* conv_nt  = (const float*)d_in[7];
  const float* s1_wih0 = (const float*)d_in[8];
  const float* s1_whh0 = (const float*)d_in[9];
  const float* s1_b0   = (const float*)d_in[10];
  const float* s1_wih1 = (const float*)d_in[11];
  const float* s1_whh1 = (const float*)d_in[12];
  const float* s1_b1   = (const float*)d_in[13];
  const float* s2_wih0 = (const float*)d_in[14];
  const float* s2_whh0 = (const float*)d_in[15];
  const float* s2_b0   = (const float*)d_in[16];
  const float* s2_wih1 = (const float*)d_in[17];
  const float* s2_whh1 = (const float*)d_in[18];
  const float* s2_b1   = (const float*)d_in[19];
  const float* bn_g    = (const float*)d_in[20];
  const float* bn_b    = (const float*)d_in[21];
  const float* prebn_g = (const float*)d_in[22];
  const float* prebn_b = (const float*)d_in[23];
  const float* fc_w0   = (const float*)d_in[24];
  const float* fc_b0   = (const float*)d_in[25];
  const float* fc_w1   = (const float*)d_in[26];
  const float* fc_b1   = (const float*)d_in[27];
  const float* fc_w2   = (const float*)d_in[28];
  const float* fc_b2   = (const float*)d_in[29];
  const float* fcbn_g0 = (const float*)d_in[30];
  const float* fcbn_b0 = (const float*)d_in[31];
  const float* fcbn_g1 = (const float*)d_in[32];
  const float* fcbn_b1 = (const float*)d_in[33];
  const int* edge_index   = (const int*)d_in[34];
  const int* node_type    = (const int*)d_in[35];
  const int* batch        = (const int*)d_in[36];
  const int* assign_src   = (const int*)d_in[37];
  const int* assign_dst   = (const int*)d_in[38];
  const int* edge_index_2 = (const int*)d_in[39];
  const int* batch_2      = (const int*)d_in[40];
  (void)in_sizes; (void)n_in; (void)out_size; (void)ws_size;

  // dynamic-LDS opt-ins (host-side, graph-capture-safe). 128KB proven r11.
  int fused_ok = (hipFuncSetAttribute((const void*)k_gru_fused,
                    hipFuncAttributeMaxDynamicSharedMemorySize, 131072) == hipSuccess);
  int tr4_ok = (hipFuncSetAttribute((const void*)k_tr4d,
                    hipFuncAttributeMaxDynamicSharedMemorySize, 65536) == hipSuccess);

  // ---- workspace layout ----
  float* Wp = (float*)d_ws;
  size_t o = 0;
  auto alloc = [&](size_t n){ float* p = Wp + o; o += n; return p; };
  float* h     = alloc((size_t)NN1*64);
  float* tr    = alloc((size_t)4*NN1*64);   // tr slabs; gi slabs in GRU fallback
  float* aggr  = alloc((size_t)NN1*64);
  float* coeff = alloc(NN1);
  float* h2    = alloc((size_t)NN2*64);
  float* cnt   = alloc(NN2);
  float* x1    = alloc(256*128);
  float* x2    = alloc(256*128);
  float* z     = alloc(256*256);
  float* z1    = alloc(256*128);
  float* z2    = alloc(256*64);
  float* stats = alloc(128);
  float* w4    = alloc(245760);
  float* wihT  = alloc(61440);
  float* wihW  = alloc(61440);
  float* whh4  = alloc(61440);
  float* s2sT1 = alloc(81920);
  float* s2sT2 = alloc(81920);
  int* etype = (int*)alloc(EE1);
  int* cnt1  = (int*)alloc(NN1);
  int* R1    = (int*)alloc(NN1 + 1);
  int* ep1   = (int*)alloc(EE1);
  int* cnt2  = (int*)alloc(NN2);
  int* R2    = (int*)alloc(NN2 + 1);
  int* ep2   = (int*)alloc(EE2);
  int* csum  = (int*)alloc(260);
  int* rb1   = (int*)alloc(257);
  int* rb2   = (int*)alloc(257);

  const int* src1 = edge_index;
  const int* dst1 = edge_index + EE1;
  const int* src2 = edge_index_2;
  const int* dst2 = edge_index_2 + EE2;

  k_etype<<<(EE1+255)/256, 256, 0, stream>>>(edge_attr, etype, EE1);
  k_copy<<<(NN1*64+255)/256, 256, 0, stream>>>(x_in, h, NN1*64);
  k_prep_msgw<<<(245760+255)/256, 256, 0, stream>>>(conv_w, w4);
  k_prep_gruw<<<(61440+255)/256, 256, 0, stream>>>(conv_wih, conv_whh, wihT, wihW, whh4);
  k_s2strans<<<(81920+255)/256, 256, 0, stream>>>(s1_wih0, s1_whh0, s1_wih1, s1_whh1, s2sT1);
  k_s2strans<<<(81920+255)/256, 256, 0, stream>>>(s2_wih0, s2_whh0, s2_wih1, s2_whh1, s2sT2);
  k_batchptr<<<(NN1+255)/256, 256, 0, stream>>>(batch, rb1, NN1, 256);
  k_batchptr<<<(NN2+255)/256, 256, 0, stream>>>(batch_2, rb2, NN2, 256);

  {  // level-1 CSR (keys = dst; ep stores packed row index t*NN1+src)
    int M = NN1, nchunk = (M + 1023)/1024;
    hipMemsetAsync(cnt1, 0, (size_t)M*sizeof(int), stream);
    k_hist<<<(EE1+255)/256, 256, 0, stream>>>(dst1, cnt1, EE1);
    k_chunksum<<<nchunk, 256, 0, stream>>>(cnt1, csum, M);
    k_chunkscan<<<1, 256, 0, stream>>>(csum, nchunk);
    k_chunkapply<<<nchunk, 256, 0, stream>>>(cnt1, csum, R1, cnt1, M);
    k_scatter<<<(EE1+255)/256, 256, 0, stream>>>(src1, dst1, etype, cnt1, ep1, EE1, NN1);
  }
  {  // level-2 CSR (single type: ep = src)
    int M = NN2, nchunk = (M + 1023)/1024;
    hipMemsetAsync(cnt2, 0, (size_t)M*sizeof(int), stream);
    k_hist<<<(EE2+255)/256, 256, 0, stream>>>(dst2, cnt2, EE2);
    k_chunksum<<<nchunk, 256, 0, stream>>>(cnt2, csum, M);
    k_chunkscan<<<1, 256, 0, stream>>>(csum, nchunk);
    k_chunkapply<<<nchunk, 256, 0, stream>>>(cnt2, csum, R2, cnt2, M);
    k_scatter<<<(EE2+255)/256, 256, 0, stream>>>(src2, dst2, nullptr, cnt2, ep2, EE2, NN2);
  }

  // GRU: fused (gi+gh+pointwise, 128KB LDS) or fallback (tr3 + finW)
  auto gru = [&](float* hbuf, int N, int lidx){
    if (fused_ok){
      k_gru_fused<<<256, 1024, 131072, stream>>>(aggr, hbuf,
          wihW + (size_t)lidx*12288, whh4 + (size_t)lidx*12288,
          conv_bih + lidx*192, conv_bhh + lidx*192, N);
    } else {
      k_tr3<<<768, 256, 0, stream>>>(aggr, wihT + (size_t)lidx*12288, tr, N);
      k_gru_finW<<<768, 256, 0, stream>>>(tr, hbuf, whh4 + (size_t)lidx*12288,
          conv_bih + lidx*192, conv_bhh + lidx*192, N);
    }
  };

  // ---- level-1: 3x MGGC(L=3) + BN + ReLU ----
  for (int i = 0; i < 3; ++i){
    k_coeff<<<(NN1+255)/256, 256, 0, stream>>>(conv_nt + i*9, node_type, coeff, NN1);
    for (int l = 0; l < 3; ++l){
      const float* W4l = w4 + (size_t)(i*3+l)*16384;   // 4 matrices, float4 layout
      if (tr4_ok){
        k_tr4d<<<512, 1024, 65536, stream>>>(h, W4l, coeff, tr, NN1);
      } else {
        for (int t = 0; t < 4; ++t)
          k_tr1<<<1024, 256, 0, stream>>>(h, W4l + (size_t)t*4096, coeff,
                                          tr + (size_t)t*NN1*64, NN1);
      }
      k_sweep_p<<<(NN1+3)/4, 256, 0, stream>>>(tr, R1, ep1, aggr, NN1);
      gru(h, NN1, i);
    }
    hipMemsetAsync(stats, 0, 128*sizeof(float), stream);
    k_bnstats<<<256, 256, 0, stream>>>(h, stats, NN1);
    k_bnapply<<<(NN1*64+255)/256, 256, 0, stream>>>(h, stats, bn_g + i*64, bn_b + i*64, NN1, 1);
  }

  // ---- set2set (single fused kernel, 1024 threads/graph) ----
  k_set2set<<<256, 1024, 0, stream>>>(h, rb1, s2sT1, s1_b0, s1_b1, x1);

  // ---- avg_pool ----
  hipMemsetAsync(h2, 0, (size_t)NN2*64*sizeof(float), stream);
  hipMemsetAsync(cnt, 0, (size_t)NN2*sizeof(float), stream);
  k_pool_acc<<<(AA*64+255)/256, 256, 0, stream>>>(h, assign_src, assign_dst, h2, cnt, AA);
  k_pool_div<<<(NN2*64+255)/256, 256, 0, stream>>>(h2, cnt, NN2);

  // ---- level-2: 2x relu(MGGC(L=3)), only edge type 0 ----
  for (int L = 3; L < 5; ++L){
    for (int l = 0; l < 3; ++l){
      const float* W4l = w4 + (size_t)(L*3+l)*16384;   // t=0 slice used
      k_tr1<<<1250, 256, 0, stream>>>(h2, W4l, nullptr, tr, NN2);
      k_sweep_p<<<(NN2+3)/4, 256, 0, stream>>>(tr, R2, ep2, aggr, NN2);
      gru(h2, NN2, L);
    }
    k_relu<<<(NN2*64+255)/256, 256, 0, stream>>>(h2, NN2*64);
  }

  k_set2set<<<256, 1024, 0, stream>>>(h2, rb2, s2sT2, s2_b0, s2_b1, x2);

  // ---- head ----
  k_concat<<<256, 256, 0, stream>>>(x1, x2, z);
  k_bn_par<<<256, 256, 0, stream>>>(z, prebn_g, prebn_b, 256, 0);
  k_fc<<<256, 128, 0, stream>>>(z, fc_w0, fc_b0, z1, 256, 128);
  k_bn_par<<<128, 256, 0, stream>>>(z1, fcbn_g0, fcbn_b0, 128, 1);
  k_fc<<<256, 64, 0, stream>>>(z1, fc_w1, fc_b1, z2, 128, 64);
  k_bn_par<<<64, 256, 0, stream>>>(z2, fcbn_g1, fcbn_b1, 64, 1);
  k_fc_out<<<4, 64, 0, stream>>>(z2, fc_w2, fc_b2, (float*)d_out);
}